// Round 3
// baseline (320.077 us; speedup 1.0000x reference)
//
#include <hip/hip_runtime.h>

typedef __attribute__((ext_vector_type(8)))  short short8;
typedef __attribute__((ext_vector_type(4)))  float f32x4;
typedef __attribute__((ext_vector_type(16))) float f32x16;

__device__ __forceinline__ short f2b(float f) {
    union { float f; unsigned u; } v; v.f = f;
    unsigned r = v.u + 0x7FFF + ((v.u >> 16) & 1);   // RNE
    return (short)(r >> 16);
}

__device__ __forceinline__ float fexp2(float x) {
    float r;
    asm("v_exp_f32 %0, %1" : "=v"(r) : "v"(x));
    return r;
}

// pack two f32 -> one u32 of 2x bf16 (RNE), lo = a, hi = b
__device__ __forceinline__ unsigned cvtpk(float a, float b) {
    unsigned r;
    asm("v_cvt_pk_bf16_f32 %0, %1, %2" : "=v"(r) : "v"(a), "v"(b));
    return r;
}

// v_permlane32_swap_b32: a' = {a.lanes[0:31], b.lanes[0:31]},
//                        b' = {a.lanes[32:63], b.lanes[32:63]}
__device__ __forceinline__ void plswap(unsigned &a, unsigned &b) {
    asm("v_permlane32_swap_b32 %0, %1" : "+v"(a), "+v"(b));
}

__device__ __forceinline__ void gll16(const void* g, void* l) {
    __builtin_amdgcn_global_load_lds(
        (const __attribute__((address_space(1))) void*)g,
        (__attribute__((address_space(3))) void*)l, 16, 0, 0);
}

// ---- prep kernels ----------------------------------------------------------

__global__ __launch_bounds__(256) void xconv_kernel(const float4* __restrict__ X,
                                                    short* __restrict__ xb) {
    int i = blockIdx.x * 256 + threadIdx.x;
    float4 v = X[i];
    short4 o;
    o.x = f2b(v.x); o.y = f2b(v.y); o.z = f2b(v.z); o.w = f2b(v.w);
    ((short4*)xb)[i] = o;
}

// 4 weight matrices fp32 [1024][1024] -> bf16 transposed, one launch (z selects)
__global__ __launch_bounds__(256) void wconv4_kernel(
    const float* __restrict__ w0, const float* __restrict__ w1,
    const float* __restrict__ w2, const float* __restrict__ w3,
    short* __restrict__ wqkvt, short* __restrict__ wot) {
    __shared__ float t[32][33];
    int z = blockIdx.z;
    const float* W = (z == 0) ? w0 : (z == 1) ? w1 : (z == 2) ? w2 : w3;
    short* WT = (z < 3) ? wqkvt : wot;
    int row_off = (z < 3) ? z * 1024 : 0;
    int bx = blockIdx.x, by = blockIdx.y;
    int c = threadIdx.x & 31, r0 = threadIdx.x >> 5;
    #pragma unroll
    for (int p = 0; p < 4; ++p) {
        int r = r0 + p * 8;
        t[r][c] = W[(size_t)(by * 32 + r) * 1024 + bx * 32 + c];
    }
    __syncthreads();
    #pragma unroll
    for (int p = 0; p < 4; ++p) {
        int r = r0 + p * 8;
        WT[(size_t)(row_off + bx * 32 + r) * 1024 + by * 32 + c] = f2b(t[c][r]);
    }
}

// V bf16 [BH][2048][64] -> Vt bf16 [BH][64][2048]
__global__ __launch_bounds__(256) void vtrans_kernel(const short* __restrict__ V,
                                                     short* __restrict__ Vt) {
    __shared__ short t[64][72];
    int st = blockIdx.x, bh = blockIdx.y;
    const size_t vbase = (size_t)bh * 2048 * 64;
    const size_t tbase = (size_t)bh * 64 * 2048;
    int tid = threadIdx.x;
    #pragma unroll
    for (int p = 0; p < 16; ++p) {
        int e = p * 256 + tid;
        int r = e >> 6, c = e & 63;
        t[r][c] = V[vbase + (size_t)(st * 64 + r) * 64 + c];
    }
    __syncthreads();
    #pragma unroll
    for (int p = 0; p < 16; ++p) {
        int e = p * 256 + tid;
        int d = e >> 6, c = e & 63;
        Vt[tbase + (size_t)d * 2048 + st * 64 + c] = t[c][d];
    }
}

// ---- MFMA GEMM: C[M,N] = A[M,K] @ Bt[N,K]^T + bias --------------------------
// mode 0: N=3072 fused QKV, scatter to Q/K/V [B,H,S,64] bf16 (Q pre-scaled by log2e/8)
// mode 1: N=1024, write fp32 row-major to Co (bias = b0)
__global__ __launch_bounds__(256) void mfma_gemm_kernel(
    const short* __restrict__ A, const short* __restrict__ Bt,
    const float* __restrict__ b0, const float* __restrict__ b1,
    const float* __restrict__ b2,
    short* __restrict__ Qo, short* __restrict__ Ko, short* __restrict__ Vo,
    float* __restrict__ Co, int K, int mode)
{
    __shared__ __align__(16) short As[2][128 * 32];
    __shared__ __align__(16) short Bs[2][128 * 32];

    const int tid = threadIdx.x;
    const int lane = tid & 63;
    const int w = tid >> 6;
    const int quad = lane >> 4;
    const int l15 = lane & 15;
    const int wm = (w & 1) * 64;
    const int wn = (w >> 1) * 64;
    const int m0 = blockIdx.y * 128;
    const int n0 = blockIdx.x * 128;

    const int rl = lane >> 2;
    const int cl = lane & 3;
    const short* srcA[2]; const short* srcB[2];
    int doff[2];
    #pragma unroll
    for (int t = 0; t < 2; ++t) {
        int row = w * 32 + t * 16 + rl;
        int sc = cl ^ (row & 3);
        srcA[t] = A  + (size_t)(m0 + row) * K + sc * 8;
        srcB[t] = Bt + (size_t)(n0 + row) * K + sc * 8;
        doff[t] = (w * 32 + t * 16) * 32;
    }

    int offA[4], offB[4];
    #pragma unroll
    for (int i = 0; i < 4; ++i) {
        int m = wm + i * 16 + l15;
        offA[i] = m * 32 + ((quad ^ (m & 3)) * 8);
        int n = wn + i * 16 + l15;
        offB[i] = n * 32 + ((quad ^ (n & 3)) * 8);
    }

    f32x4 acc[4][4];
    #pragma unroll
    for (int i = 0; i < 4; ++i)
        #pragma unroll
        for (int j = 0; j < 4; ++j)
            acc[i][j] = (f32x4){0.f, 0.f, 0.f, 0.f};

    #pragma unroll
    for (int t = 0; t < 2; ++t) {
        gll16(srcA[t], As[0] + doff[t]);
        gll16(srcB[t], Bs[0] + doff[t]);
    }
    __syncthreads();

    const int KT = K >> 5;
    for (int kt = 0; kt < KT; ++kt) {
        if (kt + 1 < KT) {
            int k1 = (kt + 1) << 5;
            int nb = (kt + 1) & 1;
            #pragma unroll
            for (int t = 0; t < 2; ++t) {
                gll16(srcA[t] + k1, As[nb] + doff[t]);
                gll16(srcB[t] + k1, Bs[nb] + doff[t]);
            }
        }
        const short* as = As[kt & 1];
        const short* bs = Bs[kt & 1];
        short8 af[4], bfr[4];
        #pragma unroll
        for (int i = 0; i < 4; ++i) af[i] = *(const short8*)(as + offA[i]);
        #pragma unroll
        for (int j = 0; j < 4; ++j) bfr[j] = *(const short8*)(bs + offB[j]);
        #pragma unroll
        for (int i = 0; i < 4; ++i)
            #pragma unroll
            for (int j = 0; j < 4; ++j)
                acc[i][j] = __builtin_amdgcn_mfma_f32_16x16x32_bf16(af[i], bfr[j], acc[i][j], 0, 0, 0);
        __syncthreads();
    }

    #pragma unroll
    for (int j = 0; j < 4; ++j) {
        int ng = n0 + wn + j * 16 + l15;
        if (mode == 0) {
            int mat = ng >> 10;
            int nl = ng & 1023;
            float bv = (mat == 0) ? b0[nl] : (mat == 1) ? b1[nl] : b2[nl];
            short* dst = (mat == 0) ? Qo : (mat == 1) ? Ko : Vo;
            float scl = (mat == 0) ? 0.18033688011112042f : 1.0f;  // log2(e)/8 folded into Q
            int hh = nl >> 6, dd = nl & 63;
            #pragma unroll
            for (int i = 0; i < 4; ++i)
                #pragma unroll
                for (int r = 0; r < 4; ++r) {
                    int mg = m0 + wm + i * 16 + quad * 4 + r;
                    int bb = mg >> 11, ss = mg & 2047;
                    dst[(((size_t)(bb * 16 + hh)) * 2048 + ss) * 64 + dd] = f2b((acc[i][j][r] + bv) * scl);
                }
        } else {
            float bv = b0[ng];
            #pragma unroll
            for (int i = 0; i < 4; ++i)
                #pragma unroll
                for (int r = 0; r < 4; ++r) {
                    int mg = m0 + wm + i * 16 + quad * 4 + r;
                    Co[(size_t)mg * 1024 + ng] = acc[i][j][r] + bv;
                }
        }
    }
}

// ---- MFMA flash attention (S^T formulation, Q in registers, no Q/P LDS) -----
// Q,K: [BH][2048][64] bf16 (Q pre-scaled by log2e/8); Vt: [BH][64][2048] bf16
// ctx out: [B][2048][1024] bf16
// grid: (bh=64, qt=16) so flat block id % 8 == bh % 8 -> same-head blocks share an XCD
__global__ __launch_bounds__(256) void attn_mfma_kernel(
    const short* __restrict__ Q, const short* __restrict__ Kg,
    const short* __restrict__ Vt, const int* __restrict__ mask,
    short* __restrict__ ctx)
{
    __shared__ __align__(16) short Ks[2][64 * 64];
    __shared__ __align__(16) short Vs[2][64 * 64];   // V^T tile: [d][key]
    __shared__ int msks[2][64];
    __shared__ float Linv[4][32];

    const int tid = threadIdx.x;
    const int lane = tid & 63;
    const int w = tid >> 6;
    const int l31 = lane & 31;
    const int hi = lane >> 5;
    const int bh = blockIdx.x;
    const int q0 = blockIdx.y * 128;
    const int h = bh & 15;
    const int b = bh >> 4;
    const size_t qkbase = (size_t)bh * 2048 * 64;
    const size_t vtbase = (size_t)bh * 64 * 2048;

    const int rl8 = lane >> 3;
    const int cl8 = lane & 7;

    const short* srcK[2]; const short* srcV[2];
    int dstoff[2];
    #pragma unroll
    for (int t = 0; t < 2; ++t) {
        int row = w * 16 + t * 8 + rl8;
        int sc = cl8 ^ (row & 7);
        srcK[t] = Kg + qkbase + (size_t)row * 64 + sc * 8;    // + kt*64 per tile
        srcV[t] = Vt + vtbase + (size_t)row * 2048 + sc * 8;  // + kt   per tile
        dstoff[t] = (w * 16 + t * 8) * 64;
    }

    // stage tile 0
    #pragma unroll
    for (int t = 0; t < 2; ++t) {
        gll16(srcK[t], Ks[0] + dstoff[t]);
        gll16(srcV[t], Vs[0] + dstoff[t]);
    }
    if (tid < 64) msks[0][tid] = mask[b * 2048 + tid];

    // Q B-frags straight from global: lane n = q = w*32+l31, k = d = s*16 + hi*8 + j
    short8 qf[4];
    {
        const short* qptr = Q + qkbase + (size_t)(q0 + w * 32 + l31) * 64;
        #pragma unroll
        for (int s = 0; s < 4; ++s)
            qf[s] = *(const short8*)(qptr + (((s << 1) | hi)) * 8);
    }

    f32x16 o[2];
    #pragma unroll
    for (int ch = 0; ch < 2; ++ch)
        #pragma unroll
        for (int r = 0; r < 16; ++r) o[ch][r] = 0.f;
    float lq[4];
    #pragma unroll
    for (int c = 0; c < 4; ++c) lq[c] = 0.f;

    __syncthreads();

    for (int t = 0; t < 32; ++t) {
        const int bidx = t & 1;
        if (t + 1 < 32) {
            const int nb = (t + 1) & 1;
            const int kt1 = (t + 1) * 64;
            #pragma unroll
            for (int s = 0; s < 2; ++s) {
                gll16(srcK[s] + (size_t)kt1 * 64, Ks[nb] + dstoff[s]);
                gll16(srcV[s] + kt1, Vs[nb] + dstoff[s]);
            }
            if (tid < 64) msks[nb][tid] = mask[b * 2048 + kt1 + tid];
        }

        const short* ks = Ks[bidx];
        const short* vs = Vs[bidx];
        unsigned long long bz = __ballot(msks[bidx][lane] == 0);

        #pragma unroll
        for (int km = 0; km < 2; ++km) {
            const int kr = km * 32 + l31;
            const int d0 = l31;          // o[0] rows
            const int d1 = 32 + l31;     // o[1] rows
            // issue all LDS reads up front: V-read latency hides under GEMM1+exp/pack
            short8 ka0 = *(const short8*)(ks + kr * 64 + (((0 << 1) | hi) ^ (l31 & 7)) * 8);
            short8 ka1 = *(const short8*)(ks + kr * 64 + (((1 << 1) | hi) ^ (l31 & 7)) * 8);
            short8 ka2 = *(const short8*)(ks + kr * 64 + (((2 << 1) | hi) ^ (l31 & 7)) * 8);
            short8 ka3 = *(const short8*)(ks + kr * 64 + (((3 << 1) | hi) ^ (l31 & 7)) * 8);
            short8 vb00 = *(const short8*)(vs + d0 * 64 + (((km * 4) | hi) ^ (d0 & 7)) * 8);
            short8 vb01 = *(const short8*)(vs + d0 * 64 + (((km * 4 + 2) | hi) ^ (d0 & 7)) * 8);
            short8 vb10 = *(const short8*)(vs + d1 * 64 + (((km * 4) | hi) ^ (d1 & 7)) * 8);
            short8 vb11 = *(const short8*)(vs + d1 * 64 + (((km * 4 + 2) | hi) ^ (d1 & 7)) * 8);

            // GEMM1: S^T (32 keys x 32 q) = K_tile . Q^T, reduce over d = 64
            f32x16 sa;
            #pragma unroll
            for (int r = 0; r < 16; ++r) sa[r] = 0.f;
            __builtin_amdgcn_s_setprio(1);
            sa = __builtin_amdgcn_mfma_f32_32x32x16_bf16(ka0, qf[0], sa, 0, 0, 0);
            sa = __builtin_amdgcn_mfma_f32_32x32x16_bf16(ka1, qf[1], sa, 0, 0, 0);
            sa = __builtin_amdgcn_mfma_f32_32x32x16_bf16(ka2, qf[2], sa, 0, 0, 0);
            sa = __builtin_amdgcn_mfma_f32_32x32x16_bf16(ka3, qf[3], sa, 0, 0, 0);
            __builtin_amdgcn_s_setprio(0);

            // p = exp2(s)  (Q carried log2e/8; no max-subtraction)
            float ps[16];
            #pragma unroll
            for (int r = 0; r < 16; ++r) ps[r] = fexp2(sa[r]);
            if (bz) {
                #pragma unroll
                for (int r = 0; r < 16; ++r) {
                    int key = km * 32 + (r & 3) + 8 * (r >> 2) + 4 * hi;
                    if (msks[bidx][key] == 0) ps[r] = 0.f;
                }
            }
            // lsum: 4 independent accumulators (short dep chains)
            #pragma unroll
            for (int c = 0; c < 4; ++c)
                lq[c] += ((ps[4 * c] + ps[4 * c + 1]) + (ps[4 * c + 2] + ps[4 * c + 3]));

            // pack to bf16 pairs (HW RNE), lane^32 exchange via permlane32_swap
            unsigned p0 = cvtpk(ps[0],  ps[1]);
            unsigned p1 = cvtpk(ps[2],  ps[3]);
            unsigned p2 = cvtpk(ps[4],  ps[5]);
            unsigned p3 = cvtpk(ps[6],  ps[7]);
            unsigned p4 = cvtpk(ps[8],  ps[9]);
            unsigned p5 = cvtpk(ps[10], ps[11]);
            unsigned p6 = cvtpk(ps[12], ps[13]);
            unsigned p7 = cvtpk(ps[14], ps[15]);
            plswap(p0, p2);
            plswap(p1, p3);
            plswap(p4, p6);
            plswap(p5, p7);

            uint4 A1u, A2u;
            A1u.x = p0; A1u.y = p1; A1u.z = p2; A1u.w = p3;
            A2u.x = p4; A2u.y = p5; A2u.z = p6; A2u.w = p7;
            short8 A1 = __builtin_bit_cast(short8, A1u);
            short8 A2 = __builtin_bit_cast(short8, A2u);

            __builtin_amdgcn_s_setprio(1);
            o[0] = __builtin_amdgcn_mfma_f32_32x32x16_bf16(A1, vb00, o[0], 0, 0, 0);
            o[0] = __builtin_amdgcn_mfma_f32_32x32x16_bf16(A2, vb01, o[0], 0, 0, 0);
            o[1] = __builtin_amdgcn_mfma_f32_32x32x16_bf16(A1, vb10, o[1], 0, 0, 0);
            o[1] = __builtin_amdgcn_mfma_f32_32x32x16_bf16(A2, vb11, o[1], 0, 0, 0);
            __builtin_amdgcn_s_setprio(0);
        }
        __syncthreads();
    }

    // epilogue: combine half-key sums (lane^32), normalize, store
    float lsum = (lq[0] + lq[1]) + (lq[2] + lq[3]);
    float ltot = lsum + __shfl_xor(lsum, 32);
    if (hi == 0) Linv[w][l31] = 1.0f / ltot;
    asm volatile("s_waitcnt lgkmcnt(0)" ::: "memory");
    float invr[16];
    #pragma unroll
    for (int r = 0; r < 16; ++r)
        invr[r] = Linv[w][(r & 3) + 8 * (r >> 2) + 4 * hi];
    #pragma unroll
    for (int ch = 0; ch < 2; ++ch)
        #pragma unroll
        for (int r = 0; r < 16; ++r) {
            int rowq = (r & 3) + 8 * (r >> 2) + 4 * hi;
            int qg = q0 + w * 32 + rowq;
            ctx[((size_t)b * 2048 + qg) * 1024 + h * 64 + ch * 32 + l31] =
                f2b(o[ch][r] * invr[r]);
        }
}

// ---- launch -----------------------------------------------------------------

extern "C" void kernel_launch(void* const* d_in, const int* in_sizes, int n_in,
                              void* d_out, int out_size, void* d_ws, size_t ws_size,
                              hipStream_t stream) {
    const size_t ME = (size_t)8192 * 1024;   // 8,388,608 elements

    char* ws = (char*)d_ws;
    short* xb    = (short*)ws; ws += ME * 2;                 // x bf16; reused as ctx
    short* wqkvt = (short*)ws; ws += (size_t)3072 * 1024 * 2;
    short* wot   = (short*)ws; ws += (size_t)1024 * 1024 * 2;
    short* Qb    = (short*)ws; ws += ME * 2;
    short* Kb    = (short*)ws; ws += ME * 2;
    short* Vb    = (short*)ws; ws += ME * 2;
    short* Vt    = (short*)ws; ws += ME * 2;

    xconv_kernel<<<8192, 256, 0, stream>>>((const float4*)d_in[0], xb);
    wconv4_kernel<<<dim3(32, 32, 4), 256, 0, stream>>>(
        (const float*)d_in[2], (const float*)d_in[4],
        (const float*)d_in[6], (const float*)d_in[8], wqkvt, wot);

    mfma_gemm_kernel<<<dim3(24, 64), 256, 0, stream>>>(
        xb, wqkvt, (const float*)d_in[3], (const float*)d_in[5], (const float*)d_in[7],
        Qb, Kb, Vb, nullptr, 1024, 0);

    vtrans_kernel<<<dim3(32, 64), 256, 0, stream>>>(Vb, Vt);

    attn_mfma_kernel<<<dim3(64, 16), 256, 0, stream>>>(
        Qb, Kb, Vt, (const int*)d_in[1], xb /* ctx */);

    mfma_gemm_kernel<<<dim3(8, 64), 256, 0, stream>>>(
        xb, wot, (const float*)d_in[9], nullptr, nullptr,
        nullptr, nullptr, nullptr, (float*)d_out, 1024, 1);
}

// Round 4
// 317.345 us; speedup vs baseline: 1.0086x; 1.0086x over previous
//
#include <hip/hip_runtime.h>

typedef __attribute__((ext_vector_type(8)))  short short8;
typedef __attribute__((ext_vector_type(4)))  float f32x4;
typedef __attribute__((ext_vector_type(16))) float f32x16;

__device__ __forceinline__ short f2b(float f) {
    union { float f; unsigned u; } v; v.f = f;
    unsigned r = v.u + 0x7FFF + ((v.u >> 16) & 1);   // RNE
    return (short)(r >> 16);
}

__device__ __forceinline__ float fexp2(float x) {
    float r;
    asm("v_exp_f32 %0, %1" : "=v"(r) : "v"(x));
    return r;
}

// pack two f32 -> one u32 of 2x bf16 (RNE), lo = a, hi = b
__device__ __forceinline__ unsigned cvtpk(float a, float b) {
    unsigned r;
    asm("v_cvt_pk_bf16_f32 %0, %1, %2" : "=v"(r) : "v"(a), "v"(b));
    return r;
}

// v_permlane32_swap_b32: a' = {a.lanes[0:31], b.lanes[0:31]},
//                        b' = {a.lanes[32:63], b.lanes[32:63]}
__device__ __forceinline__ void plswap(unsigned &a, unsigned &b) {
    asm("v_permlane32_swap_b32 %0, %1" : "+v"(a), "+v"(b));
}

__device__ __forceinline__ void gll16(const void* g, void* l) {
    __builtin_amdgcn_global_load_lds(
        (const __attribute__((address_space(1))) void*)g,
        (__attribute__((address_space(3))) void*)l, 16, 0, 0);
}

// ---- prep kernels ----------------------------------------------------------

__global__ __launch_bounds__(256) void xconv_kernel(const float4* __restrict__ X,
                                                    short* __restrict__ xb) {
    int i = blockIdx.x * 256 + threadIdx.x;
    float4 v = X[i];
    short4 o;
    o.x = f2b(v.x); o.y = f2b(v.y); o.z = f2b(v.z); o.w = f2b(v.w);
    ((short4*)xb)[i] = o;
}

// 4 weight matrices fp32 [1024][1024] -> bf16 transposed, one launch (z selects)
__global__ __launch_bounds__(256) void wconv4_kernel(
    const float* __restrict__ w0, const float* __restrict__ w1,
    const float* __restrict__ w2, const float* __restrict__ w3,
    short* __restrict__ wqkvt, short* __restrict__ wot) {
    __shared__ float t[32][33];
    int z = blockIdx.z;
    const float* W = (z == 0) ? w0 : (z == 1) ? w1 : (z == 2) ? w2 : w3;
    short* WT = (z < 3) ? wqkvt : wot;
    int row_off = (z < 3) ? z * 1024 : 0;
    int bx = blockIdx.x, by = blockIdx.y;
    int c = threadIdx.x & 31, r0 = threadIdx.x >> 5;
    #pragma unroll
    for (int p = 0; p < 4; ++p) {
        int r = r0 + p * 8;
        t[r][c] = W[(size_t)(by * 32 + r) * 1024 + bx * 32 + c];
    }
    __syncthreads();
    #pragma unroll
    for (int p = 0; p < 4; ++p) {
        int r = r0 + p * 8;
        WT[(size_t)(row_off + bx * 32 + r) * 1024 + by * 32 + c] = f2b(t[c][r]);
    }
}

// V bf16 [BH][2048][64] -> Vt bf16 [BH][64][2048]
__global__ __launch_bounds__(256) void vtrans_kernel(const short* __restrict__ V,
                                                     short* __restrict__ Vt) {
    __shared__ short t[64][72];
    int st = blockIdx.x, bh = blockIdx.y;
    const size_t vbase = (size_t)bh * 2048 * 64;
    const size_t tbase = (size_t)bh * 64 * 2048;
    int tid = threadIdx.x;
    #pragma unroll
    for (int p = 0; p < 16; ++p) {
        int e = p * 256 + tid;
        int r = e >> 6, c = e & 63;
        t[r][c] = V[vbase + (size_t)(st * 64 + r) * 64 + c];
    }
    __syncthreads();
    #pragma unroll
    for (int p = 0; p < 16; ++p) {
        int e = p * 256 + tid;
        int d = e >> 6, c = e & 63;
        Vt[tbase + (size_t)d * 2048 + st * 64 + c] = t[c][d];
    }
}

// ---- MFMA GEMM: C[M,N] = A[M,K] @ Bt[N,K]^T + bias --------------------------
// mode 0: N=3072 fused QKV, scatter to Q/K/V [B,H,S,64] bf16 (Q pre-scaled by log2e/8)
// mode 1: N=1024, write fp32 row-major to Co (bias = b0)
__global__ __launch_bounds__(256) void mfma_gemm_kernel(
    const short* __restrict__ A, const short* __restrict__ Bt,
    const float* __restrict__ b0, const float* __restrict__ b1,
    const float* __restrict__ b2,
    short* __restrict__ Qo, short* __restrict__ Ko, short* __restrict__ Vo,
    float* __restrict__ Co, int K, int mode)
{
    __shared__ __align__(16) short As[2][128 * 32];
    __shared__ __align__(16) short Bs[2][128 * 32];

    const int tid = threadIdx.x;
    const int lane = tid & 63;
    const int w = tid >> 6;
    const int quad = lane >> 4;
    const int l15 = lane & 15;
    const int wm = (w & 1) * 64;
    const int wn = (w >> 1) * 64;
    const int m0 = blockIdx.y * 128;
    const int n0 = blockIdx.x * 128;

    const int rl = lane >> 2;
    const int cl = lane & 3;
    const short* srcA[2]; const short* srcB[2];
    int doff[2];
    #pragma unroll
    for (int t = 0; t < 2; ++t) {
        int row = w * 32 + t * 16 + rl;
        int sc = cl ^ (row & 3);
        srcA[t] = A  + (size_t)(m0 + row) * K + sc * 8;
        srcB[t] = Bt + (size_t)(n0 + row) * K + sc * 8;
        doff[t] = (w * 32 + t * 16) * 32;
    }

    int offA[4], offB[4];
    #pragma unroll
    for (int i = 0; i < 4; ++i) {
        int m = wm + i * 16 + l15;
        offA[i] = m * 32 + ((quad ^ (m & 3)) * 8);
        int n = wn + i * 16 + l15;
        offB[i] = n * 32 + ((quad ^ (n & 3)) * 8);
    }

    f32x4 acc[4][4];
    #pragma unroll
    for (int i = 0; i < 4; ++i)
        #pragma unroll
        for (int j = 0; j < 4; ++j)
            acc[i][j] = (f32x4){0.f, 0.f, 0.f, 0.f};

    #pragma unroll
    for (int t = 0; t < 2; ++t) {
        gll16(srcA[t], As[0] + doff[t]);
        gll16(srcB[t], Bs[0] + doff[t]);
    }
    __syncthreads();

    const int KT = K >> 5;
    for (int kt = 0; kt < KT; ++kt) {
        if (kt + 1 < KT) {
            int k1 = (kt + 1) << 5;
            int nb = (kt + 1) & 1;
            #pragma unroll
            for (int t = 0; t < 2; ++t) {
                gll16(srcA[t] + k1, As[nb] + doff[t]);
                gll16(srcB[t] + k1, Bs[nb] + doff[t]);
            }
        }
        const short* as = As[kt & 1];
        const short* bs = Bs[kt & 1];
        short8 af[4], bfr[4];
        #pragma unroll
        for (int i = 0; i < 4; ++i) af[i] = *(const short8*)(as + offA[i]);
        #pragma unroll
        for (int j = 0; j < 4; ++j) bfr[j] = *(const short8*)(bs + offB[j]);
        #pragma unroll
        for (int i = 0; i < 4; ++i)
            #pragma unroll
            for (int j = 0; j < 4; ++j)
                acc[i][j] = __builtin_amdgcn_mfma_f32_16x16x32_bf16(af[i], bfr[j], acc[i][j], 0, 0, 0);
        __syncthreads();
    }

    #pragma unroll
    for (int j = 0; j < 4; ++j) {
        int ng = n0 + wn + j * 16 + l15;
        if (mode == 0) {
            int mat = ng >> 10;
            int nl = ng & 1023;
            float bv = (mat == 0) ? b0[nl] : (mat == 1) ? b1[nl] : b2[nl];
            short* dst = (mat == 0) ? Qo : (mat == 1) ? Ko : Vo;
            float scl = (mat == 0) ? 0.18033688011112042f : 1.0f;  // log2(e)/8 folded into Q
            int hh = nl >> 6, dd = nl & 63;
            #pragma unroll
            for (int i = 0; i < 4; ++i)
                #pragma unroll
                for (int r = 0; r < 4; ++r) {
                    int mg = m0 + wm + i * 16 + quad * 4 + r;
                    int bb = mg >> 11, ss = mg & 2047;
                    dst[(((size_t)(bb * 16 + hh)) * 2048 + ss) * 64 + dd] = f2b((acc[i][j][r] + bv) * scl);
                }
        } else {
            float bv = b0[ng];
            #pragma unroll
            for (int i = 0; i < 4; ++i)
                #pragma unroll
                for (int r = 0; r < 4; ++r) {
                    int mg = m0 + wm + i * 16 + quad * 4 + r;
                    Co[(size_t)mg * 1024 + ng] = acc[i][j][r] + bv;
                }
        }
    }
}

// ---- MFMA flash attention (S^T formulation, Q in registers, no Q/P LDS) -----
// Q,K: [BH][2048][64] bf16 (Q pre-scaled by log2e/8); Vt: [BH][64][2048] bf16
// ctx out: [B][2048][1024] bf16
// R1-proven schedule (inline LDS reads, no setprio) + persistent-zero MFMA C
// operand (kills 16 v_mov per km-block) + split lsum accumulators.
__global__ __launch_bounds__(256) void attn_mfma_kernel(
    const short* __restrict__ Q, const short* __restrict__ Kg,
    const short* __restrict__ Vt, const int* __restrict__ mask,
    short* __restrict__ ctx)
{
    __shared__ __align__(16) short Ks[2][64 * 64];
    __shared__ __align__(16) short Vs[2][64 * 64];   // V^T tile: [d][key]
    __shared__ int msks[2][64];
    __shared__ float Linv[4][32];

    const int tid = threadIdx.x;
    const int lane = tid & 63;
    const int w = tid >> 6;
    const int l31 = lane & 31;
    const int hi = lane >> 5;
    const int bh = blockIdx.x;
    const int q0 = blockIdx.y * 128;
    const int h = bh & 15;
    const int b = bh >> 4;
    const size_t qkbase = (size_t)bh * 2048 * 64;
    const size_t vtbase = (size_t)bh * 64 * 2048;

    const int rl8 = lane >> 3;
    const int cl8 = lane & 7;

    const short* srcK[2]; const short* srcV[2];
    int dstoff[2];
    #pragma unroll
    for (int t = 0; t < 2; ++t) {
        int row = w * 16 + t * 8 + rl8;
        int sc = cl8 ^ (row & 7);
        srcK[t] = Kg + qkbase + (size_t)row * 64 + sc * 8;    // + kt*64 per tile
        srcV[t] = Vt + vtbase + (size_t)row * 2048 + sc * 8;  // + kt   per tile
        dstoff[t] = (w * 16 + t * 8) * 64;
    }

    // stage tile 0
    #pragma unroll
    for (int t = 0; t < 2; ++t) {
        gll16(srcK[t], Ks[0] + dstoff[t]);
        gll16(srcV[t], Vs[0] + dstoff[t]);
    }
    if (tid < 64) msks[0][tid] = mask[b * 2048 + tid];

    // Q B-frags straight from global: lane n = q = w*32+l31, k = d = s*16 + hi*8 + j
    short8 qf[4];
    {
        const short* qptr = Q + qkbase + (size_t)(q0 + w * 32 + l31) * 64;
        #pragma unroll
        for (int s = 0; s < 4; ++s)
            qf[s] = *(const short8*)(qptr + (((s << 1) | hi)) * 8);
    }

    // persistent zero C-operand: lets GEMM1 write its accumulator fresh
    // (no 16x v_mov zero-init per km-block)
    f32x16 zz;
    #pragma unroll
    for (int r = 0; r < 16; ++r) zz[r] = 0.f;

    f32x16 o[2];
    #pragma unroll
    for (int ch = 0; ch < 2; ++ch)
        #pragma unroll
        for (int r = 0; r < 16; ++r) o[ch][r] = 0.f;
    float lq[4];
    #pragma unroll
    for (int c = 0; c < 4; ++c) lq[c] = 0.f;

    __syncthreads();

    for (int t = 0; t < 32; ++t) {
        const int bidx = t & 1;
        if (t + 1 < 32) {
            const int nb = (t + 1) & 1;
            const int kt1 = (t + 1) * 64;
            #pragma unroll
            for (int s = 0; s < 2; ++s) {
                gll16(srcK[s] + (size_t)kt1 * 64, Ks[nb] + dstoff[s]);
                gll16(srcV[s] + kt1, Vs[nb] + dstoff[s]);
            }
            if (tid < 64) msks[nb][tid] = mask[b * 2048 + kt1 + tid];
        }

        const short* ks = Ks[bidx];
        const short* vs = Vs[bidx];
        unsigned long long bz = __ballot(msks[bidx][lane] == 0);

        #pragma unroll
        for (int km = 0; km < 2; ++km) {
            // GEMM1: S^T (32 keys x 32 q) = K_tile . Q^T, reduce over d = 64
            const int kr = km * 32 + l31;
            short8 ka0 = *(const short8*)(ks + kr * 64 + ((hi ^ (l31 & 7))) * 8);
            f32x16 sa = __builtin_amdgcn_mfma_f32_32x32x16_bf16(ka0, qf[0], zz, 0, 0, 0);
            #pragma unroll
            for (int s = 1; s < 4; ++s) {
                short8 ka = *(const short8*)(ks + kr * 64 + (((s << 1) | hi) ^ (l31 & 7)) * 8);
                sa = __builtin_amdgcn_mfma_f32_32x32x16_bf16(ka, qf[s], sa, 0, 0, 0);
            }
            // p = exp2(s)  (Q carried log2e/8; no max-subtraction)
            float ps[16];
            #pragma unroll
            for (int r = 0; r < 16; ++r) ps[r] = fexp2(sa[r]);
            if (bz) {
                #pragma unroll
                for (int r = 0; r < 16; ++r) {
                    int key = km * 32 + (r & 3) + 8 * (r >> 2) + 4 * hi;
                    if (msks[bidx][key] == 0) ps[r] = 0.f;
                }
            }
            // lsum: 4 independent accumulators (short dep chains)
            #pragma unroll
            for (int c = 0; c < 4; ++c)
                lq[c] += ((ps[4 * c] + ps[4 * c + 1]) + (ps[4 * c + 2] + ps[4 * c + 3]));

            // pack to bf16 pairs (HW RNE), lane^32 exchange via permlane32_swap
            unsigned p0 = cvtpk(ps[0],  ps[1]);
            unsigned p1 = cvtpk(ps[2],  ps[3]);
            unsigned p2 = cvtpk(ps[4],  ps[5]);
            unsigned p3 = cvtpk(ps[6],  ps[7]);
            unsigned p4 = cvtpk(ps[8],  ps[9]);
            unsigned p5 = cvtpk(ps[10], ps[11]);
            unsigned p6 = cvtpk(ps[12], ps[13]);
            unsigned p7 = cvtpk(ps[14], ps[15]);
            plswap(p0, p2);
            plswap(p1, p3);
            plswap(p4, p6);
            plswap(p5, p7);

            uint4 A1u, A2u;
            A1u.x = p0; A1u.y = p1; A1u.z = p2; A1u.w = p3;
            A2u.x = p4; A2u.y = p5; A2u.z = p6; A2u.w = p7;
            short8 A1 = __builtin_bit_cast(short8, A1u);
            short8 A2 = __builtin_bit_cast(short8, A2u);

            #pragma unroll
            for (int ch = 0; ch < 2; ++ch) {
                const int d = ch * 32 + l31;
                short8 vb0 = *(const short8*)(vs + d * 64 + (((km * 4) | hi) ^ (d & 7)) * 8);
                short8 vb1 = *(const short8*)(vs + d * 64 + (((km * 4 + 2) | hi) ^ (d & 7)) * 8);
                o[ch] = __builtin_amdgcn_mfma_f32_32x32x16_bf16(A1, vb0, o[ch], 0, 0, 0);
                o[ch] = __builtin_amdgcn_mfma_f32_32x32x16_bf16(A2, vb1, o[ch], 0, 0, 0);
            }
        }
        __syncthreads();
    }

    // epilogue: combine half-key sums (lane^32), normalize, store
    float lsum = (lq[0] + lq[1]) + (lq[2] + lq[3]);
    float ltot = lsum + __shfl_xor(lsum, 32);
    if (hi == 0) Linv[w][l31] = 1.0f / ltot;
    asm volatile("s_waitcnt lgkmcnt(0)" ::: "memory");
    float invr[16];
    #pragma unroll
    for (int r = 0; r < 16; ++r)
        invr[r] = Linv[w][(r & 3) + 8 * (r >> 2) + 4 * hi];
    #pragma unroll
    for (int ch = 0; ch < 2; ++ch)
        #pragma unroll
        for (int r = 0; r < 16; ++r) {
            int rowq = (r & 3) + 8 * (r >> 2) + 4 * hi;
            int qg = q0 + w * 32 + rowq;
            ctx[((size_t)b * 2048 + qg) * 1024 + h * 64 + ch * 32 + l31] =
                f2b(o[ch][r] * invr[r]);
        }
}

// ---- launch -----------------------------------------------------------------

extern "C" void kernel_launch(void* const* d_in, const int* in_sizes, int n_in,
                              void* d_out, int out_size, void* d_ws, size_t ws_size,
                              hipStream_t stream) {
    const size_t ME = (size_t)8192 * 1024;   // 8,388,608 elements

    char* ws = (char*)d_ws;
    short* xb    = (short*)ws; ws += ME * 2;                 // x bf16; reused as ctx
    short* wqkvt = (short*)ws; ws += (size_t)3072 * 1024 * 2;
    short* wot   = (short*)ws; ws += (size_t)1024 * 1024 * 2;
    short* Qb    = (short*)ws; ws += ME * 2;
    short* Kb    = (short*)ws; ws += ME * 2;
    short* Vb    = (short*)ws; ws += ME * 2;
    short* Vt    = (short*)ws; ws += ME * 2;

    xconv_kernel<<<8192, 256, 0, stream>>>((const float4*)d_in[0], xb);
    wconv4_kernel<<<dim3(32, 32, 4), 256, 0, stream>>>(
        (const float*)d_in[2], (const float*)d_in[4],
        (const float*)d_in[6], (const float*)d_in[8], wqkvt, wot);

    mfma_gemm_kernel<<<dim3(24, 64), 256, 0, stream>>>(
        xb, wqkvt, (const float*)d_in[3], (const float*)d_in[5], (const float*)d_in[7],
        Qb, Kb, Vb, nullptr, 1024, 0);

    vtrans_kernel<<<dim3(32, 64), 256, 0, stream>>>(Vb, Vt);

    attn_mfma_kernel<<<dim3(64, 16), 256, 0, stream>>>(
        Qb, Kb, Vt, (const int*)d_in[1], xb /* ctx */);

    mfma_gemm_kernel<<<dim3(8, 64), 256, 0, stream>>>(
        xb, wot, (const float*)d_in[9], nullptr, nullptr,
        nullptr, nullptr, nullptr, (float*)d_out, 1024, 1);
}

// Round 6
// 304.470 us; speedup vs baseline: 1.0513x; 1.0423x over previous
//
#include <hip/hip_runtime.h>

typedef __attribute__((ext_vector_type(8)))  short short8;
typedef __attribute__((ext_vector_type(4)))  float f32x4;
typedef __attribute__((ext_vector_type(16))) float f32x16;

__device__ __forceinline__ short f2b(float f) {
    union { float f; unsigned u; } v; v.f = f;
    unsigned r = v.u + 0x7FFF + ((v.u >> 16) & 1);   // RNE
    return (short)(r >> 16);
}

__device__ __forceinline__ float fexp2(float x) {
    float r;
    asm("v_exp_f32 %0, %1" : "=v"(r) : "v"(x));
    return r;
}

// pack two f32 -> one u32 of 2x bf16 (RNE), lo = a, hi = b
__device__ __forceinline__ unsigned cvtpk(float a, float b) {
    unsigned r;
    asm("v_cvt_pk_bf16_f32 %0, %1, %2" : "=v"(r) : "v"(a), "v"(b));
    return r;
}

// v_permlane32_swap_b32: a' = {a.lanes[0:31], b.lanes[0:31]},
//                        b' = {a.lanes[32:63], b.lanes[32:63]}
__device__ __forceinline__ void plswap(unsigned &a, unsigned &b) {
    asm("v_permlane32_swap_b32 %0, %1" : "+v"(a), "+v"(b));
}

__device__ __forceinline__ void gll16(const void* g, void* l) {
    __builtin_amdgcn_global_load_lds(
        (const __attribute__((address_space(1))) void*)g,
        (__attribute__((address_space(3))) void*)l, 16, 0, 0);
}

// ---- prep kernels ----------------------------------------------------------

__global__ __launch_bounds__(256) void xconv_kernel(const float4* __restrict__ X,
                                                    short* __restrict__ xb) {
    int i = blockIdx.x * 256 + threadIdx.x;
    float4 v = X[i];
    short4 o;
    o.x = f2b(v.x); o.y = f2b(v.y); o.z = f2b(v.z); o.w = f2b(v.w);
    ((short4*)xb)[i] = o;
}

// 4 weight matrices fp32 [1024][1024] -> bf16 transposed, one launch (z selects)
__global__ __launch_bounds__(256) void wconv4_kernel(
    const float* __restrict__ w0, const float* __restrict__ w1,
    const float* __restrict__ w2, const float* __restrict__ w3,
    short* __restrict__ wqkvt, short* __restrict__ wot) {
    __shared__ float t[32][33];
    int z = blockIdx.z;
    const float* W = (z == 0) ? w0 : (z == 1) ? w1 : (z == 2) ? w2 : w3;
    short* WT = (z < 3) ? wqkvt : wot;
    int row_off = (z < 3) ? z * 1024 : 0;
    int bx = blockIdx.x, by = blockIdx.y;
    int c = threadIdx.x & 31, r0 = threadIdx.x >> 5;
    #pragma unroll
    for (int p = 0; p < 4; ++p) {
        int r = r0 + p * 8;
        t[r][c] = W[(size_t)(by * 32 + r) * 1024 + bx * 32 + c];
    }
    __syncthreads();
    #pragma unroll
    for (int p = 0; p < 4; ++p) {
        int r = r0 + p * 8;
        WT[(size_t)(row_off + bx * 32 + r) * 1024 + by * 32 + c] = f2b(t[c][r]);
    }
}

// V bf16 [BH][2048][64] -> Vt bf16 [BH][64][2048]
__global__ __launch_bounds__(256) void vtrans_kernel(const short* __restrict__ V,
                                                     short* __restrict__ Vt) {
    __shared__ short t[64][72];
    int st = blockIdx.x, bh = blockIdx.y;
    const size_t vbase = (size_t)bh * 2048 * 64;
    const size_t tbase = (size_t)bh * 64 * 2048;
    int tid = threadIdx.x;
    #pragma unroll
    for (int p = 0; p < 16; ++p) {
        int e = p * 256 + tid;
        int r = e >> 6, c = e & 63;
        t[r][c] = V[vbase + (size_t)(st * 64 + r) * 64 + c];
    }
    __syncthreads();
    #pragma unroll
    for (int p = 0; p < 16; ++p) {
        int e = p * 256 + tid;
        int d = e >> 6, c = e & 63;
        Vt[tbase + (size_t)d * 2048 + st * 64 + c] = t[c][d];
    }
}

// ---- MFMA GEMM: C[M,N] = A[M,K] @ Bt[N,K]^T + bias --------------------------
// mode 0: N=3072 fused QKV, scatter to Q/K/V [B,H,S,64] bf16 (Q pre-scaled by log2e/8)
// mode 1: N=1024, write fp32 row-major to Co (bias = b0)
__global__ __launch_bounds__(256) void mfma_gemm_kernel(
    const short* __restrict__ A, const short* __restrict__ Bt,
    const float* __restrict__ b0, const float* __restrict__ b1,
    const float* __restrict__ b2,
    short* __restrict__ Qo, short* __restrict__ Ko, short* __restrict__ Vo,
    float* __restrict__ Co, int K, int mode)
{
    __shared__ __align__(16) short As[2][128 * 32];
    __shared__ __align__(16) short Bs[2][128 * 32];

    const int tid = threadIdx.x;
    const int lane = tid & 63;
    const int w = tid >> 6;
    const int quad = lane >> 4;
    const int l15 = lane & 15;
    const int wm = (w & 1) * 64;
    const int wn = (w >> 1) * 64;
    const int m0 = blockIdx.y * 128;
    const int n0 = blockIdx.x * 128;

    const int rl = lane >> 2;
    const int cl = lane & 3;
    const short* srcA[2]; const short* srcB[2];
    int doff[2];
    #pragma unroll
    for (int t = 0; t < 2; ++t) {
        int row = w * 32 + t * 16 + rl;
        int sc = cl ^ (row & 3);
        srcA[t] = A  + (size_t)(m0 + row) * K + sc * 8;
        srcB[t] = Bt + (size_t)(n0 + row) * K + sc * 8;
        doff[t] = (w * 32 + t * 16) * 32;
    }

    int offA[4], offB[4];
    #pragma unroll
    for (int i = 0; i < 4; ++i) {
        int m = wm + i * 16 + l15;
        offA[i] = m * 32 + ((quad ^ (m & 3)) * 8);
        int n = wn + i * 16 + l15;
        offB[i] = n * 32 + ((quad ^ (n & 3)) * 8);
    }

    f32x4 acc[4][4];
    #pragma unroll
    for (int i = 0; i < 4; ++i)
        #pragma unroll
        for (int j = 0; j < 4; ++j)
            acc[i][j] = (f32x4){0.f, 0.f, 0.f, 0.f};

    #pragma unroll
    for (int t = 0; t < 2; ++t) {
        gll16(srcA[t], As[0] + doff[t]);
        gll16(srcB[t], Bs[0] + doff[t]);
    }
    __syncthreads();

    const int KT = K >> 5;
    for (int kt = 0; kt < KT; ++kt) {
        if (kt + 1 < KT) {
            int k1 = (kt + 1) << 5;
            int nb = (kt + 1) & 1;
            #pragma unroll
            for (int t = 0; t < 2; ++t) {
                gll16(srcA[t] + k1, As[nb] + doff[t]);
                gll16(srcB[t] + k1, Bs[nb] + doff[t]);
            }
        }
        const short* as = As[kt & 1];
        const short* bs = Bs[kt & 1];
        short8 af[4], bfr[4];
        #pragma unroll
        for (int i = 0; i < 4; ++i) af[i] = *(const short8*)(as + offA[i]);
        #pragma unroll
        for (int j = 0; j < 4; ++j) bfr[j] = *(const short8*)(bs + offB[j]);
        #pragma unroll
        for (int i = 0; i < 4; ++i)
            #pragma unroll
            for (int j = 0; j < 4; ++j)
                acc[i][j] = __builtin_amdgcn_mfma_f32_16x16x32_bf16(af[i], bfr[j], acc[i][j], 0, 0, 0);
        __syncthreads();
    }

    #pragma unroll
    for (int j = 0; j < 4; ++j) {
        int ng = n0 + wn + j * 16 + l15;
        if (mode == 0) {
            int mat = ng >> 10;
            int nl = ng & 1023;
            float bv = (mat == 0) ? b0[nl] : (mat == 1) ? b1[nl] : b2[nl];
            short* dst = (mat == 0) ? Qo : (mat == 1) ? Ko : Vo;
            float scl = (mat == 0) ? 0.18033688011112042f : 1.0f;  // log2(e)/8 folded into Q
            int hh = nl >> 6, dd = nl & 63;
            #pragma unroll
            for (int i = 0; i < 4; ++i)
                #pragma unroll
                for (int r = 0; r < 4; ++r) {
                    int mg = m0 + wm + i * 16 + quad * 4 + r;
                    int bb = mg >> 11, ss = mg & 2047;
                    dst[(((size_t)(bb * 16 + hh)) * 2048 + ss) * 64 + dd] = f2b((acc[i][j][r] + bv) * scl);
                }
        } else {
            float bv = b0[ng];
            #pragma unroll
            for (int i = 0; i < 4; ++i)
                #pragma unroll
                for (int r = 0; r < 4; ++r) {
                    int mg = m0 + wm + i * 16 + quad * 4 + r;
                    Co[(size_t)mg * 1024 + ng] = acc[i][j][r] + bv;
                }
        }
    }
}

// ---- MFMA flash attention (S^T formulation, Q in registers, no Q/P LDS) -----
// Q,K: [BH][2048][64] bf16 (Q pre-scaled by log2e/8); Vt: [BH][64][2048] bf16
// ctx out: [B][2048][1024] bf16
// Each wave handles TWO q-subtiles (q and q+128): K/V LDS fragments are loaded
// once and feed both, halving LDS-read cycles per unit work and doubling the
// independent dependency chains (latency hiding). Staging/mask/barrier logic
// is byte-identical to the proven 4-wave kernel.
__global__ __launch_bounds__(256) void attn_mfma_kernel(
    const short* __restrict__ Q, const short* __restrict__ Kg,
    const short* __restrict__ Vt, const int* __restrict__ mask,
    short* __restrict__ ctx)
{
    __shared__ __align__(16) short Ks[2][64 * 64];
    __shared__ __align__(16) short Vs[2][64 * 64];   // V^T tile: [d][key]
    __shared__ int msks[2][64];
    __shared__ float LinvA[4][32];
    __shared__ float LinvB[4][32];

    const int tid = threadIdx.x;
    const int lane = tid & 63;
    const int w = tid >> 6;
    const int l31 = lane & 31;
    const int hi = lane >> 5;
    const int bh = blockIdx.x;
    const int q0 = blockIdx.y * 256;
    const int h = bh & 15;
    const int b = bh >> 4;
    const size_t qkbase = (size_t)bh * 2048 * 64;
    const size_t vtbase = (size_t)bh * 64 * 2048;

    const int rl8 = lane >> 3;
    const int cl8 = lane & 7;

    const short* srcK[2]; const short* srcV[2];
    int dstoff[2];
    #pragma unroll
    for (int t = 0; t < 2; ++t) {
        int row = w * 16 + t * 8 + rl8;
        int sc = cl8 ^ (row & 7);
        srcK[t] = Kg + qkbase + (size_t)row * 64 + sc * 8;    // + kt*64 per tile
        srcV[t] = Vt + vtbase + (size_t)row * 2048 + sc * 8;  // + kt   per tile
        dstoff[t] = (w * 16 + t * 8) * 64;
    }

    // stage tile 0
    #pragma unroll
    for (int t = 0; t < 2; ++t) {
        gll16(srcK[t], Ks[0] + dstoff[t]);
        gll16(srcV[t], Vs[0] + dstoff[t]);
    }
    if (tid < 64) msks[0][tid] = mask[b * 2048 + tid];

    // Q B-frags for both q-subtiles: lane n = q, k = d = s*16 + hi*8 + j
    short8 qfa[4], qfb[4];
    {
        const short* qptrA = Q + qkbase + (size_t)(q0 + w * 32 + l31) * 64;
        const short* qptrB = qptrA + 128 * 64;
        #pragma unroll
        for (int s = 0; s < 4; ++s) {
            qfa[s] = *(const short8*)(qptrA + (((s << 1) | hi)) * 8);
            qfb[s] = *(const short8*)(qptrB + (((s << 1) | hi)) * 8);
        }
    }

    // persistent zero C-operand for GEMM1
    f32x16 zz;
    #pragma unroll
    for (int r = 0; r < 16; ++r) zz[r] = 0.f;

    f32x16 oa[2], ob[2];
    #pragma unroll
    for (int ch = 0; ch < 2; ++ch)
        #pragma unroll
        for (int r = 0; r < 16; ++r) { oa[ch][r] = 0.f; ob[ch][r] = 0.f; }
    float lqa[4], lqb[4];
    #pragma unroll
    for (int c = 0; c < 4; ++c) { lqa[c] = 0.f; lqb[c] = 0.f; }

    __syncthreads();

    for (int t = 0; t < 32; ++t) {
        const int bidx = t & 1;
        if (t + 1 < 32) {
            const int nb = (t + 1) & 1;
            const int kt1 = (t + 1) * 64;
            #pragma unroll
            for (int s = 0; s < 2; ++s) {
                gll16(srcK[s] + (size_t)kt1 * 64, Ks[nb] + dstoff[s]);
                gll16(srcV[s] + kt1, Vs[nb] + dstoff[s]);
            }
            if (tid < 64) msks[nb][tid] = mask[b * 2048 + kt1 + tid];
        }

        const short* ks = Ks[bidx];
        const short* vs = Vs[bidx];
        unsigned long long bz = __ballot(msks[bidx][lane] == 0);

        #pragma unroll
        for (int km = 0; km < 2; ++km) {
            // GEMM1: S^T (32 keys x 32 q) = K_tile . Q^T, reduce over d = 64
            // K-frags loaded once, feed BOTH q-subtile chains.
            const int kr = km * 32 + l31;
            short8 ka0 = *(const short8*)(ks + kr * 64 + ((hi ^ (l31 & 7))) * 8);
            short8 ka1 = *(const short8*)(ks + kr * 64 + (((2 | hi)) ^ (l31 & 7)) * 8);
            short8 ka2 = *(const short8*)(ks + kr * 64 + (((4 | hi)) ^ (l31 & 7)) * 8);
            short8 ka3 = *(const short8*)(ks + kr * 64 + (((6 | hi)) ^ (l31 & 7)) * 8);
            f32x16 saA = __builtin_amdgcn_mfma_f32_32x32x16_bf16(ka0, qfa[0], zz, 0, 0, 0);
            f32x16 saB = __builtin_amdgcn_mfma_f32_32x32x16_bf16(ka0, qfb[0], zz, 0, 0, 0);
            saA = __builtin_amdgcn_mfma_f32_32x32x16_bf16(ka1, qfa[1], saA, 0, 0, 0);
            saB = __builtin_amdgcn_mfma_f32_32x32x16_bf16(ka1, qfb[1], saB, 0, 0, 0);
            saA = __builtin_amdgcn_mfma_f32_32x32x16_bf16(ka2, qfa[2], saA, 0, 0, 0);
            saB = __builtin_amdgcn_mfma_f32_32x32x16_bf16(ka2, qfb[2], saB, 0, 0, 0);
            saA = __builtin_amdgcn_mfma_f32_32x32x16_bf16(ka3, qfa[3], saA, 0, 0, 0);
            saB = __builtin_amdgcn_mfma_f32_32x32x16_bf16(ka3, qfb[3], saB, 0, 0, 0);

            // p = exp2(s)  (Q carried log2e/8; no max-subtraction)
            float psA[16], psB[16];
            #pragma unroll
            for (int r = 0; r < 16; ++r) { psA[r] = fexp2(saA[r]); psB[r] = fexp2(saB[r]); }
            if (bz) {
                #pragma unroll
                for (int r = 0; r < 16; ++r) {
                    int key = km * 32 + (r & 3) + 8 * (r >> 2) + 4 * hi;
                    if (msks[bidx][key] == 0) { psA[r] = 0.f; psB[r] = 0.f; }
                }
            }
            #pragma unroll
            for (int c = 0; c < 4; ++c) {
                lqa[c] += ((psA[4 * c] + psA[4 * c + 1]) + (psA[4 * c + 2] + psA[4 * c + 3]));
                lqb[c] += ((psB[4 * c] + psB[4 * c + 1]) + (psB[4 * c + 2] + psB[4 * c + 3]));
            }

            // pack to bf16 pairs (HW RNE), lane^32 exchange via permlane32_swap
            unsigned a0 = cvtpk(psA[0],  psA[1]);
            unsigned a1 = cvtpk(psA[2],  psA[3]);
            unsigned a2 = cvtpk(psA[4],  psA[5]);
            unsigned a3 = cvtpk(psA[6],  psA[7]);
            unsigned a4 = cvtpk(psA[8],  psA[9]);
            unsigned a5 = cvtpk(psA[10], psA[11]);
            unsigned a6 = cvtpk(psA[12], psA[13]);
            unsigned a7 = cvtpk(psA[14], psA[15]);
            plswap(a0, a2); plswap(a1, a3); plswap(a4, a6); plswap(a5, a7);
            uint4 A1au, A2au;
            A1au.x = a0; A1au.y = a1; A1au.z = a2; A1au.w = a3;
            A2au.x = a4; A2au.y = a5; A2au.z = a6; A2au.w = a7;
            short8 A1a = __builtin_bit_cast(short8, A1au);
            short8 A2a = __builtin_bit_cast(short8, A2au);

            unsigned g0 = cvtpk(psB[0],  psB[1]);
            unsigned g1 = cvtpk(psB[2],  psB[3]);
            unsigned g2 = cvtpk(psB[4],  psB[5]);
            unsigned g3 = cvtpk(psB[6],  psB[7]);
            unsigned g4 = cvtpk(psB[8],  psB[9]);
            unsigned g5 = cvtpk(psB[10], psB[11]);
            unsigned g6 = cvtpk(psB[12], psB[13]);
            unsigned g7 = cvtpk(psB[14], psB[15]);
            plswap(g0, g2); plswap(g1, g3); plswap(g4, g6); plswap(g5, g7);
            uint4 B1u, B2u;
            B1u.x = g0; B1u.y = g1; B1u.z = g2; B1u.w = g3;
            B2u.x = g4; B2u.y = g5; B2u.z = g6; B2u.w = g7;
            short8 A1b = __builtin_bit_cast(short8, B1u);
            short8 A2b = __builtin_bit_cast(short8, B2u);

            // GEMM2: V-frags loaded once, feed BOTH q-subtile accumulators.
            #pragma unroll
            for (int ch = 0; ch < 2; ++ch) {
                const int d = ch * 32 + l31;
                short8 vb0 = *(const short8*)(vs + d * 64 + (((km * 4) | hi) ^ (d & 7)) * 8);
                short8 vb1 = *(const short8*)(vs + d * 64 + (((km * 4 + 2) | hi) ^ (d & 7)) * 8);
                oa[ch] = __builtin_amdgcn_mfma_f32_32x32x16_bf16(A1a, vb0, oa[ch], 0, 0, 0);
                ob[ch] = __builtin_amdgcn_mfma_f32_32x32x16_bf16(A1b, vb0, ob[ch], 0, 0, 0);
                oa[ch] = __builtin_amdgcn_mfma_f32_32x32x16_bf16(A2a, vb1, oa[ch], 0, 0, 0);
                ob[ch] = __builtin_amdgcn_mfma_f32_32x32x16_bf16(A2b, vb1, ob[ch], 0, 0, 0);
            }
        }
        __syncthreads();
    }

    // epilogue: combine half-key sums (lane^32), normalize, store (both sets)
    float lsumA = (lqa[0] + lqa[1]) + (lqa[2] + lqa[3]);
    float ltotA = lsumA + __shfl_xor(lsumA, 32);
    float lsumB = (lqb[0] + lqb[1]) + (lqb[2] + lqb[3]);
    float ltotB = lsumB + __shfl_xor(lsumB, 32);
    if (hi == 0) {
        LinvA[w][l31] = 1.0f / ltotA;
        LinvB[w][l31] = 1.0f / ltotB;
    }
    asm volatile("s_waitcnt lgkmcnt(0)" ::: "memory");
    float invrA[16], invrB[16];
    #pragma unroll
    for (int r = 0; r < 16; ++r) {
        int rowq = (r & 3) + 8 * (r >> 2) + 4 * hi;
        invrA[r] = LinvA[w][rowq];
        invrB[r] = LinvB[w][rowq];
    }
    #pragma unroll
    for (int ch = 0; ch < 2; ++ch)
        #pragma unroll
        for (int r = 0; r < 16; ++r) {
            int rowq = (r & 3) + 8 * (r >> 2) + 4 * hi;
            int qg = q0 + w * 32 + rowq;
            size_t base = ((size_t)b * 2048 + qg) * 1024 + h * 64 + ch * 32 + l31;
            ctx[base] = f2b(oa[ch][r] * invrA[r]);
            ctx[base + (size_t)128 * 1024] = f2b(ob[ch][r] * invrB[r]);
        }
}

// ---- launch -----------------------------------------------------------------

extern "C" void kernel_launch(void* const* d_in, const int* in_sizes, int n_in,
                              void* d_out, int out_size, void* d_ws, size_t ws_size,
                              hipStream_t stream) {
    const size_t ME = (size_t)8192 * 1024;   // 8,388,608 elements

    char* ws = (char*)d_ws;
    short* xb    = (short*)ws; ws += ME * 2;                 // x bf16; reused as ctx
    short* wqkvt = (short*)ws; ws += (size_t)3072 * 1024 * 2;
    short* wot   = (short*)ws; ws += (size_t)1024 * 1024 * 2;
    short* Qb    = (short*)ws; ws += ME * 2;
    short* Kb    = (short*)ws; ws += ME * 2;
    short* Vb    = (short*)ws; ws += ME * 2;
    short* Vt    = (short*)ws; ws += ME * 2;

    xconv_kernel<<<8192, 256, 0, stream>>>((const float4*)d_in[0], xb);
    wconv4_kernel<<<dim3(32, 32, 4), 256, 0, stream>>>(
        (const float*)d_in[2], (const float*)d_in[4],
        (const float*)d_in[6], (const float*)d_in[8], wqkvt, wot);

    mfma_gemm_kernel<<<dim3(24, 64), 256, 0, stream>>>(
        xb, wqkvt, (const float*)d_in[3], (const float*)d_in[5], (const float*)d_in[7],
        Qb, Kb, Vb, nullptr, 1024, 0);

    vtrans_kernel<<<dim3(32, 64), 256, 0, stream>>>(Vb, Vt);

    attn_mfma_kernel<<<dim3(64, 8), 256, 0, stream>>>(
        Qb, Kb, Vt, (const int*)d_in[1], xb /* ctx */);

    mfma_gemm_kernel<<<dim3(8, 64), 256, 0, stream>>>(
        xb, wot, (const float*)d_in[9], nullptr, nullptr,
        nullptr, nullptr, nullptr, (float*)d_out, 1024, 1);
}

// Round 8
// 300.305 us; speedup vs baseline: 1.0658x; 1.0139x over previous
//
#include <hip/hip_runtime.h>

typedef __attribute__((ext_vector_type(8)))  short short8;
typedef __attribute__((ext_vector_type(4)))  float f32x4;
typedef __attribute__((ext_vector_type(16))) float f32x16;

__device__ __forceinline__ short f2b(float f) {
    union { float f; unsigned u; } v; v.f = f;
    unsigned r = v.u + 0x7FFF + ((v.u >> 16) & 1);   // RNE
    return (short)(r >> 16);
}

__device__ __forceinline__ float fexp2(float x) {
    float r;
    asm("v_exp_f32 %0, %1" : "=v"(r) : "v"(x));
    return r;
}

// pack two f32 -> one u32 of 2x bf16 (RNE), lo = a, hi = b
__device__ __forceinline__ unsigned cvtpk(float a, float b) {
    unsigned r;
    asm("v_cvt_pk_bf16_f32 %0, %1, %2" : "=v"(r) : "v"(a), "v"(b));
    return r;
}

// v_permlane32_swap_b32: a' = {a.lanes[0:31], b.lanes[0:31]},
//                        b' = {a.lanes[32:63], b.lanes[32:63]}
__device__ __forceinline__ void plswap(unsigned &a, unsigned &b) {
    asm("v_permlane32_swap_b32 %0, %1" : "+v"(a), "+v"(b));
}

__device__ __forceinline__ void gll16(const void* g, void* l) {
    __builtin_amdgcn_global_load_lds(
        (const __attribute__((address_space(1))) void*)g,
        (__attribute__((address_space(3))) void*)l, 16, 0, 0);
}

// ---- prep kernels ----------------------------------------------------------

__global__ __launch_bounds__(256) void xconv_kernel(const float4* __restrict__ X,
                                                    short* __restrict__ xb) {
    int i = blockIdx.x * 256 + threadIdx.x;
    float4 v = X[i];
    short4 o;
    o.x = f2b(v.x); o.y = f2b(v.y); o.z = f2b(v.z); o.w = f2b(v.w);
    ((short4*)xb)[i] = o;
}

// 4 weight matrices fp32 [1024][1024] -> bf16 transposed, one launch (z selects)
__global__ __launch_bounds__(256) void wconv4_kernel(
    const float* __restrict__ w0, const float* __restrict__ w1,
    const float* __restrict__ w2, const float* __restrict__ w3,
    short* __restrict__ wqkvt, short* __restrict__ wot) {
    __shared__ float t[32][33];
    int z = blockIdx.z;
    const float* W = (z == 0) ? w0 : (z == 1) ? w1 : (z == 2) ? w2 : w3;
    short* WT = (z < 3) ? wqkvt : wot;
    int row_off = (z < 3) ? z * 1024 : 0;
    int bx = blockIdx.x, by = blockIdx.y;
    int c = threadIdx.x & 31, r0 = threadIdx.x >> 5;
    #pragma unroll
    for (int p = 0; p < 4; ++p) {
        int r = r0 + p * 8;
        t[r][c] = W[(size_t)(by * 32 + r) * 1024 + bx * 32 + c];
    }
    __syncthreads();
    #pragma unroll
    for (int p = 0; p < 4; ++p) {
        int r = r0 + p * 8;
        WT[(size_t)(row_off + bx * 32 + r) * 1024 + by * 32 + c] = f2b(t[c][r]);
    }
}

// ---- MFMA GEMM: C[M,N] = A[M,K] @ Bt[N,K]^T + bias --------------------------
// mode 0: N=3072 fused QKV, scatter to Q/K [B,H,S,64] bf16 (Q pre-scaled by
//         log2e/8); V written DIRECTLY TRANSPOSED to Vo = Vt [BH][64][2048]
//         (4 consecutive acc rows = 4 consecutive s -> one short4 store).
// mode 1: N=1024, write fp32 row-major to Co (bias = b0)
__global__ __launch_bounds__(256) void mfma_gemm_kernel(
    const short* __restrict__ A, const short* __restrict__ Bt,
    const float* __restrict__ b0, const float* __restrict__ b1,
    const float* __restrict__ b2,
    short* __restrict__ Qo, short* __restrict__ Ko, short* __restrict__ Vo,
    float* __restrict__ Co, int K, int mode)
{
    __shared__ __align__(16) short As[2][128 * 32];
    __shared__ __align__(16) short Bs[2][128 * 32];

    const int tid = threadIdx.x;
    const int lane = tid & 63;
    const int w = tid >> 6;
    const int quad = lane >> 4;
    const int l15 = lane & 15;
    const int wm = (w & 1) * 64;
    const int wn = (w >> 1) * 64;
    const int m0 = blockIdx.y * 128;
    const int n0 = blockIdx.x * 128;

    const int rl = lane >> 2;
    const int cl = lane & 3;
    const short* srcA[2]; const short* srcB[2];
    int doff[2];
    #pragma unroll
    for (int t = 0; t < 2; ++t) {
        int row = w * 32 + t * 16 + rl;
        int sc = cl ^ (row & 3);
        srcA[t] = A  + (size_t)(m0 + row) * K + sc * 8;
        srcB[t] = Bt + (size_t)(n0 + row) * K + sc * 8;
        doff[t] = (w * 32 + t * 16) * 32;
    }

    int offA[4], offB[4];
    #pragma unroll
    for (int i = 0; i < 4; ++i) {
        int m = wm + i * 16 + l15;
        offA[i] = m * 32 + ((quad ^ (m & 3)) * 8);
        int n = wn + i * 16 + l15;
        offB[i] = n * 32 + ((quad ^ (n & 3)) * 8);
    }

    f32x4 acc[4][4];
    #pragma unroll
    for (int i = 0; i < 4; ++i)
        #pragma unroll
        for (int j = 0; j < 4; ++j)
            acc[i][j] = (f32x4){0.f, 0.f, 0.f, 0.f};

    #pragma unroll
    for (int t = 0; t < 2; ++t) {
        gll16(srcA[t], As[0] + doff[t]);
        gll16(srcB[t], Bs[0] + doff[t]);
    }
    __syncthreads();

    const int KT = K >> 5;
    for (int kt = 0; kt < KT; ++kt) {
        if (kt + 1 < KT) {
            int k1 = (kt + 1) << 5;
            int nb = (kt + 1) & 1;
            #pragma unroll
            for (int t = 0; t < 2; ++t) {
                gll16(srcA[t] + k1, As[nb] + doff[t]);
                gll16(srcB[t] + k1, Bs[nb] + doff[t]);
            }
        }
        const short* as = As[kt & 1];
        const short* bs = Bs[kt & 1];
        short8 af[4], bfr[4];
        #pragma unroll
        for (int i = 0; i < 4; ++i) af[i] = *(const short8*)(as + offA[i]);
        #pragma unroll
        for (int j = 0; j < 4; ++j) bfr[j] = *(const short8*)(bs + offB[j]);
        #pragma unroll
        for (int i = 0; i < 4; ++i)
            #pragma unroll
            for (int j = 0; j < 4; ++j)
                acc[i][j] = __builtin_amdgcn_mfma_f32_16x16x32_bf16(af[i], bfr[j], acc[i][j], 0, 0, 0);
        __syncthreads();
    }

    #pragma unroll
    for (int j = 0; j < 4; ++j) {
        int ng = n0 + wn + j * 16 + l15;
        if (mode == 0) {
            int mat = ng >> 10;
            int nl = ng & 1023;
            float bv = (mat == 0) ? b0[nl] : (mat == 1) ? b1[nl] : b2[nl];
            int hh = nl >> 6, dd = nl & 63;
            if (mat == 2) {
                // V -> Vt [BH][64][2048]: 4 consecutive rows r are 4
                // consecutive s -> one aligned short4 store per (i,j).
                #pragma unroll
                for (int i = 0; i < 4; ++i) {
                    int mg0 = m0 + wm + i * 16 + quad * 4;
                    int bb = mg0 >> 11, ss0 = mg0 & 2047;
                    short4 vv;
                    vv.x = f2b(acc[i][j][0] + bv);
                    vv.y = f2b(acc[i][j][1] + bv);
                    vv.z = f2b(acc[i][j][2] + bv);
                    vv.w = f2b(acc[i][j][3] + bv);
                    *(short4*)&Vo[((size_t)(bb * 16 + hh) * 64 + dd) * 2048 + ss0] = vv;
                }
            } else {
                short* dst = (mat == 0) ? Qo : Ko;
                float scl = (mat == 0) ? 0.18033688011112042f : 1.0f;  // log2(e)/8 folded into Q
                #pragma unroll
                for (int i = 0; i < 4; ++i)
                    #pragma unroll
                    for (int r = 0; r < 4; ++r) {
                        int mg = m0 + wm + i * 16 + quad * 4 + r;
                        int bb = mg >> 11, ss = mg & 2047;
                        dst[(((size_t)(bb * 16 + hh)) * 2048 + ss) * 64 + dd] = f2b((acc[i][j][r] + bv) * scl);
                    }
            }
        } else {
            float bv = b0[ng];
            #pragma unroll
            for (int i = 0; i < 4; ++i)
                #pragma unroll
                for (int r = 0; r < 4; ++r) {
                    int mg = m0 + wm + i * 16 + quad * 4 + r;
                    Co[(size_t)mg * 1024 + ng] = acc[i][j][r] + bv;
                }
        }
    }
}

// ---- MFMA flash attention (S^T formulation, Q in registers, no Q/P LDS) -----
// Q,K: [BH][2048][64] bf16 (Q pre-scaled by log2e/8); Vt: [BH][64][2048] bf16
// ctx out: [B][2048][1024] bf16
// Each wave handles TWO q-subtiles (q and q+128): K/V LDS fragments are loaded
// once and feed both, halving LDS-read cycles per unit work and doubling the
// independent dependency chains (latency hiding). Staging/mask/barrier logic
// is byte-identical to the proven 4-wave kernel.
__global__ __launch_bounds__(256) void attn_mfma_kernel(
    const short* __restrict__ Q, const short* __restrict__ Kg,
    const short* __restrict__ Vt, const int* __restrict__ mask,
    short* __restrict__ ctx)
{
    __shared__ __align__(16) short Ks[2][64 * 64];
    __shared__ __align__(16) short Vs[2][64 * 64];   // V^T tile: [d][key]
    __shared__ int msks[2][64];
    __shared__ float LinvA[4][32];
    __shared__ float LinvB[4][32];

    const int tid = threadIdx.x;
    const int lane = tid & 63;
    const int w = tid >> 6;
    const int l31 = lane & 31;
    const int hi = lane >> 5;
    const int bh = blockIdx.x;
    const int q0 = blockIdx.y * 256;
    const int h = bh & 15;
    const int b = bh >> 4;
    const size_t qkbase = (size_t)bh * 2048 * 64;
    const size_t vtbase = (size_t)bh * 64 * 2048;

    const int rl8 = lane >> 3;
    const int cl8 = lane & 7;

    const short* srcK[2]; const short* srcV[2];
    int dstoff[2];
    #pragma unroll
    for (int t = 0; t < 2; ++t) {
        int row = w * 16 + t * 8 + rl8;
        int sc = cl8 ^ (row & 7);
        srcK[t] = Kg + qkbase + (size_t)row * 64 + sc * 8;    // + kt*64 per tile
        srcV[t] = Vt + vtbase + (size_t)row * 2048 + sc * 8;  // + kt   per tile
        dstoff[t] = (w * 16 + t * 8) * 64;
    }

    // stage tile 0
    #pragma unroll
    for (int t = 0; t < 2; ++t) {
        gll16(srcK[t], Ks[0] + dstoff[t]);
        gll16(srcV[t], Vs[0] + dstoff[t]);
    }
    if (tid < 64) msks[0][tid] = mask[b * 2048 + tid];

    // Q B-frags for both q-subtiles: lane n = q, k = d = s*16 + hi*8 + j
    short8 qfa[4], qfb[4];
    {
        const short* qptrA = Q + qkbase + (size_t)(q0 + w * 32 + l31) * 64;
        const short* qptrB = qptrA + 128 * 64;
        #pragma unroll
        for (int s = 0; s < 4; ++s) {
            qfa[s] = *(const short8*)(qptrA + (((s << 1) | hi)) * 8);
            qfb[s] = *(const short8*)(qptrB + (((s << 1) | hi)) * 8);
        }
    }

    // persistent zero C-operand for GEMM1
    f32x16 zz;
    #pragma unroll
    for (int r = 0; r < 16; ++r) zz[r] = 0.f;

    f32x16 oa[2], ob[2];
    #pragma unroll
    for (int ch = 0; ch < 2; ++ch)
        #pragma unroll
        for (int r = 0; r < 16; ++r) { oa[ch][r] = 0.f; ob[ch][r] = 0.f; }
    float lqa[4], lqb[4];
    #pragma unroll
    for (int c = 0; c < 4; ++c) { lqa[c] = 0.f; lqb[c] = 0.f; }

    __syncthreads();

    for (int t = 0; t < 32; ++t) {
        const int bidx = t & 1;
        if (t + 1 < 32) {
            const int nb = (t + 1) & 1;
            const int kt1 = (t + 1) * 64;
            #pragma unroll
            for (int s = 0; s < 2; ++s) {
                gll16(srcK[s] + (size_t)kt1 * 64, Ks[nb] + dstoff[s]);
                gll16(srcV[s] + kt1, Vs[nb] + dstoff[s]);
            }
            if (tid < 64) msks[nb][tid] = mask[b * 2048 + kt1 + tid];
        }

        const short* ks = Ks[bidx];
        const short* vs = Vs[bidx];
        unsigned long long bz = __ballot(msks[bidx][lane] == 0);

        #pragma unroll
        for (int km = 0; km < 2; ++km) {
            // GEMM1: S^T (32 keys x 32 q) = K_tile . Q^T, reduce over d = 64
            // K-frags loaded once, feed BOTH q-subtile chains.
            const int kr = km * 32 + l31;
            short8 ka0 = *(const short8*)(ks + kr * 64 + ((hi ^ (l31 & 7))) * 8);
            short8 ka1 = *(const short8*)(ks + kr * 64 + (((2 | hi)) ^ (l31 & 7)) * 8);
            short8 ka2 = *(const short8*)(ks + kr * 64 + (((4 | hi)) ^ (l31 & 7)) * 8);
            short8 ka3 = *(const short8*)(ks + kr * 64 + (((6 | hi)) ^ (l31 & 7)) * 8);
            f32x16 saA = __builtin_amdgcn_mfma_f32_32x32x16_bf16(ka0, qfa[0], zz, 0, 0, 0);
            f32x16 saB = __builtin_amdgcn_mfma_f32_32x32x16_bf16(ka0, qfb[0], zz, 0, 0, 0);
            saA = __builtin_amdgcn_mfma_f32_32x32x16_bf16(ka1, qfa[1], saA, 0, 0, 0);
            saB = __builtin_amdgcn_mfma_f32_32x32x16_bf16(ka1, qfb[1], saB, 0, 0, 0);
            saA = __builtin_amdgcn_mfma_f32_32x32x16_bf16(ka2, qfa[2], saA, 0, 0, 0);
            saB = __builtin_amdgcn_mfma_f32_32x32x16_bf16(ka2, qfb[2], saB, 0, 0, 0);
            saA = __builtin_amdgcn_mfma_f32_32x32x16_bf16(ka3, qfa[3], saA, 0, 0, 0);
            saB = __builtin_amdgcn_mfma_f32_32x32x16_bf16(ka3, qfb[3], saB, 0, 0, 0);

            // p = exp2(s)  (Q carried log2e/8; no max-subtraction)
            float psA[16], psB[16];
            #pragma unroll
            for (int r = 0; r < 16; ++r) { psA[r] = fexp2(saA[r]); psB[r] = fexp2(saB[r]); }
            if (bz) {
                #pragma unroll
                for (int r = 0; r < 16; ++r) {
                    int key = km * 32 + (r & 3) + 8 * (r >> 2) + 4 * hi;
                    if (msks[bidx][key] == 0) { psA[r] = 0.f; psB[r] = 0.f; }
                }
            }
            #pragma unroll
            for (int c = 0; c < 4; ++c) {
                lqa[c] += ((psA[4 * c] + psA[4 * c + 1]) + (psA[4 * c + 2] + psA[4 * c + 3]));
                lqb[c] += ((psB[4 * c] + psB[4 * c + 1]) + (psB[4 * c + 2] + psB[4 * c + 3]));
            }

            // pack to bf16 pairs (HW RNE), lane^32 exchange via permlane32_swap
            unsigned a0 = cvtpk(psA[0],  psA[1]);
            unsigned a1 = cvtpk(psA[2],  psA[3]);
            unsigned a2 = cvtpk(psA[4],  psA[5]);
            unsigned a3 = cvtpk(psA[6],  psA[7]);
            unsigned a4 = cvtpk(psA[8],  psA[9]);
            unsigned a5 = cvtpk(psA[10], psA[11]);
            unsigned a6 = cvtpk(psA[12], psA[13]);
            unsigned a7 = cvtpk(psA[14], psA[15]);
            plswap(a0, a2); plswap(a1, a3); plswap(a4, a6); plswap(a5, a7);
            uint4 A1au, A2au;
            A1au.x = a0; A1au.y = a1; A1au.z = a2; A1au.w = a3;
            A2au.x = a4; A2au.y = a5; A2au.z = a6; A2au.w = a7;
            short8 A1a = __builtin_bit_cast(short8, A1au);
            short8 A2a = __builtin_bit_cast(short8, A2au);

            unsigned g0 = cvtpk(psB[0],  psB[1]);
            unsigned g1 = cvtpk(psB[2],  psB[3]);
            unsigned g2 = cvtpk(psB[4],  psB[5]);
            unsigned g3 = cvtpk(psB[6],  psB[7]);
            unsigned g4 = cvtpk(psB[8],  psB[9]);
            unsigned g5 = cvtpk(psB[10], psB[11]);
            unsigned g6 = cvtpk(psB[12], psB[13]);
            unsigned g7 = cvtpk(psB[14], psB[15]);
            plswap(g0, g2); plswap(g1, g3); plswap(g4, g6); plswap(g5, g7);
            uint4 B1u, B2u;
            B1u.x = g0; B1u.y = g1; B1u.z = g2; B1u.w = g3;
            B2u.x = g4; B2u.y = g5; B2u.z = g6; B2u.w = g7;
            short8 A1b = __builtin_bit_cast(short8, B1u);
            short8 A2b = __builtin_bit_cast(short8, B2u);

            // GEMM2: V-frags loaded once, feed BOTH q-subtile accumulators.
            #pragma unroll
            for (int ch = 0; ch < 2; ++ch) {
                const int d = ch * 32 + l31;
                short8 vb0 = *(const short8*)(vs + d * 64 + (((km * 4) | hi) ^ (d & 7)) * 8);
                short8 vb1 = *(const short8*)(vs + d * 64 + (((km * 4 + 2) | hi) ^ (d & 7)) * 8);
                oa[ch] = __builtin_amdgcn_mfma_f32_32x32x16_bf16(A1a, vb0, oa[ch], 0, 0, 0);
                ob[ch] = __builtin_amdgcn_mfma_f32_32x32x16_bf16(A1b, vb0, ob[ch], 0, 0, 0);
                oa[ch] = __builtin_amdgcn_mfma_f32_32x32x16_bf16(A2a, vb1, oa[ch], 0, 0, 0);
                ob[ch] = __builtin_amdgcn_mfma_f32_32x32x16_bf16(A2b, vb1, ob[ch], 0, 0, 0);
            }
        }
        __syncthreads();
    }

    // epilogue: combine half-key sums (lane^32), normalize, store (both sets)
    float lsumA = (lqa[0] + lqa[1]) + (lqa[2] + lqa[3]);
    float ltotA = lsumA + __shfl_xor(lsumA, 32);
    float lsumB = (lqb[0] + lqb[1]) + (lqb[2] + lqb[3]);
    float ltotB = lsumB + __shfl_xor(lsumB, 32);
    if (hi == 0) {
        LinvA[w][l31] = 1.0f / ltotA;
        LinvB[w][l31] = 1.0f / ltotB;
    }
    asm volatile("s_waitcnt lgkmcnt(0)" ::: "memory");
    float invrA[16], invrB[16];
    #pragma unroll
    for (int r = 0; r < 16; ++r) {
        int rowq = (r & 3) + 8 * (r >> 2) + 4 * hi;
        invrA[r] = LinvA[w][rowq];
        invrB[r] = LinvB[w][rowq];
    }
    #pragma unroll
    for (int ch = 0; ch < 2; ++ch)
        #pragma unroll
        for (int r = 0; r < 16; ++r) {
            int rowq = (r & 3) + 8 * (r >> 2) + 4 * hi;
            int qg = q0 + w * 32 + rowq;
            size_t base = ((size_t)b * 2048 + qg) * 1024 + h * 64 + ch * 32 + l31;
            ctx[base] = f2b(oa[ch][r] * invrA[r]);
            ctx[base + (size_t)128 * 1024] = f2b(ob[ch][r] * invrB[r]);
        }
}

// ---- launch -----------------------------------------------------------------

extern "C" void kernel_launch(void* const* d_in, const int* in_sizes, int n_in,
                              void* d_out, int out_size, void* d_ws, size_t ws_size,
                              hipStream_t stream) {
    const size_t ME = (size_t)8192 * 1024;   // 8,388,608 elements

    char* ws = (char*)d_ws;
    short* xb    = (short*)ws; ws += ME * 2;                 // x bf16; reused as ctx
    short* wqkvt = (short*)ws; ws += (size_t)3072 * 1024 * 2;
    short* wot   = (short*)ws; ws += (size_t)1024 * 1024 * 2;
    short* Qb    = (short*)ws; ws += ME * 2;
    short* Kb    = (short*)ws; ws += ME * 2;
    short* Vt    = (short*)ws; ws += ME * 2;   // V^T written directly by the QKV GEMM

    xconv_kernel<<<8192, 256, 0, stream>>>((const float4*)d_in[0], xb);
    wconv4_kernel<<<dim3(32, 32, 4), 256, 0, stream>>>(
        (const float*)d_in[2], (const float*)d_in[4],
        (const float*)d_in[6], (const float*)d_in[8], wqkvt, wot);

    mfma_gemm_kernel<<<dim3(24, 64), 256, 0, stream>>>(
        xb, wqkvt, (const float*)d_in[3], (const float*)d_in[5], (const float*)d_in[7],
        Qb, Kb, Vt, nullptr, 1024, 0);

    attn_mfma_kernel<<<dim3(64, 8), 256, 0, stream>>>(
        Qb, Kb, Vt, (const int*)d_in[1], xb /* ctx */);

    mfma_gemm_kernel<<<dim3(8, 64), 256, 0, stream>>>(
        xb, wot, (const float*)d_in[9], nullptr, nullptr,
        nullptr, nullptr, nullptr, (float*)d_out, 1024, 1);
}

// Round 9
// 295.568 us; speedup vs baseline: 1.0829x; 1.0160x over previous
//
#include <hip/hip_runtime.h>

typedef __attribute__((ext_vector_type(8)))  short short8;
typedef __attribute__((ext_vector_type(4)))  float f32x4;
typedef __attribute__((ext_vector_type(16))) float f32x16;

__device__ __forceinline__ short f2b(float f) {
    union { float f; unsigned u; } v; v.f = f;
    unsigned r = v.u + 0x7FFF + ((v.u >> 16) & 1);   // RNE
    return (short)(r >> 16);
}

__device__ __forceinline__ float fexp2(float x) {
    float r;
    asm("v_exp_f32 %0, %1" : "=v"(r) : "v"(x));
    return r;
}

// pack two f32 -> one u32 of 2x bf16 (RNE), lo = a, hi = b
__device__ __forceinline__ unsigned cvtpk(float a, float b) {
    unsigned r;
    asm("v_cvt_pk_bf16_f32 %0, %1, %2" : "=v"(r) : "v"(a), "v"(b));
    return r;
}

// v_permlane32_swap_b32: a' = {a.lanes[0:31], b.lanes[0:31]},
//                        b' = {a.lanes[32:63], b.lanes[32:63]}
__device__ __forceinline__ void plswap(unsigned &a, unsigned &b) {
    asm("v_permlane32_swap_b32 %0, %1" : "+v"(a), "+v"(b));
}

__device__ __forceinline__ void gll16(const void* g, void* l) {
    __builtin_amdgcn_global_load_lds(
        (const __attribute__((address_space(1))) void*)g,
        (__attribute__((address_space(3))) void*)l, 16, 0, 0);
}

// ---- prep kernels ----------------------------------------------------------

__global__ __launch_bounds__(256) void xconv_kernel(const float4* __restrict__ X,
                                                    short* __restrict__ xb) {
    int i = blockIdx.x * 256 + threadIdx.x;
    float4 v = X[i];
    short4 o;
    o.x = f2b(v.x); o.y = f2b(v.y); o.z = f2b(v.z); o.w = f2b(v.w);
    ((short4*)xb)[i] = o;
}

// 4 weight matrices fp32 [1024][1024] -> bf16 transposed, one launch (z selects)
__global__ __launch_bounds__(256) void wconv4_kernel(
    const float* __restrict__ w0, const float* __restrict__ w1,
    const float* __restrict__ w2, const float* __restrict__ w3,
    short* __restrict__ wqkvt, short* __restrict__ wot) {
    __shared__ float t[32][33];
    int z = blockIdx.z;
    const float* W = (z == 0) ? w0 : (z == 1) ? w1 : (z == 2) ? w2 : w3;
    short* WT = (z < 3) ? wqkvt : wot;
    int row_off = (z < 3) ? z * 1024 : 0;
    int bx = blockIdx.x, by = blockIdx.y;
    int c = threadIdx.x & 31, r0 = threadIdx.x >> 5;
    #pragma unroll
    for (int p = 0; p < 4; ++p) {
        int r = r0 + p * 8;
        t[r][c] = W[(size_t)(by * 32 + r) * 1024 + bx * 32 + c];
    }
    __syncthreads();
    #pragma unroll
    for (int p = 0; p < 4; ++p) {
        int r = r0 + p * 8;
        WT[(size_t)(row_off + bx * 32 + r) * 1024 + by * 32 + c] = f2b(t[c][r]);
    }
}

// ---- QKV MFMA GEMM: BM=256 x BN=128, per-wave 128x64 output -----------------
// A-fragment reuse: 12 ds_read_b128 feed 32 MFMA per K-step (vs 8:16) ->
// MFMA-bound instead of LDS-read-bound. Same proven staging idiom / 1 barrier
// per K-step / 4 waves. Scatter epilogue identical to the proven mode-0 path
// (V written directly transposed), only the i-loop extends to 8.
__global__ __launch_bounds__(256, 2) void mfma_gemm_qkv_kernel(
    const short* __restrict__ A, const short* __restrict__ Bt,
    const float* __restrict__ b0, const float* __restrict__ b1,
    const float* __restrict__ b2,
    short* __restrict__ Qo, short* __restrict__ Ko, short* __restrict__ Vo,
    int K)
{
    __shared__ __align__(16) short As[2][256 * 32];   // 32 KB
    __shared__ __align__(16) short Bs[2][128 * 32];   // 16 KB

    const int tid = threadIdx.x;
    const int lane = tid & 63;
    const int w = tid >> 6;
    const int quad = lane >> 4;
    const int l15 = lane & 15;
    const int wm = (w & 1) * 128;
    const int wn = (w >> 1) * 64;
    const int m0 = blockIdx.y * 256;
    const int n0 = blockIdx.x * 128;

    const int rl = lane >> 2;
    const int cl = lane & 3;
    const short* srcA[4]; int doffA[4];
    #pragma unroll
    for (int t = 0; t < 4; ++t) {
        int row = w * 64 + t * 16 + rl;
        int sc = cl ^ (row & 3);
        srcA[t] = A + (size_t)(m0 + row) * K + sc * 8;
        doffA[t] = (w * 64 + t * 16) * 32;
    }
    const short* srcB[2]; int doffB[2];
    #pragma unroll
    for (int t = 0; t < 2; ++t) {
        int row = w * 32 + t * 16 + rl;
        int sc = cl ^ (row & 3);
        srcB[t] = Bt + (size_t)(n0 + row) * K + sc * 8;
        doffB[t] = (w * 32 + t * 16) * 32;
    }

    int offA[8], offB[4];
    #pragma unroll
    for (int i = 0; i < 8; ++i) {
        int m = wm + i * 16 + l15;
        offA[i] = m * 32 + ((quad ^ (m & 3)) * 8);
    }
    #pragma unroll
    for (int j = 0; j < 4; ++j) {
        int n = wn + j * 16 + l15;
        offB[j] = n * 32 + ((quad ^ (n & 3)) * 8);
    }

    f32x4 acc[8][4];
    #pragma unroll
    for (int i = 0; i < 8; ++i)
        #pragma unroll
        for (int j = 0; j < 4; ++j)
            acc[i][j] = (f32x4){0.f, 0.f, 0.f, 0.f};

    #pragma unroll
    for (int t = 0; t < 4; ++t) gll16(srcA[t], As[0] + doffA[t]);
    #pragma unroll
    for (int t = 0; t < 2; ++t) gll16(srcB[t], Bs[0] + doffB[t]);
    __syncthreads();

    const int KT = K >> 5;
    for (int kt = 0; kt < KT; ++kt) {
        if (kt + 1 < KT) {
            int k1 = (kt + 1) << 5;
            int nb = (kt + 1) & 1;
            #pragma unroll
            for (int t = 0; t < 4; ++t) gll16(srcA[t] + k1, As[nb] + doffA[t]);
            #pragma unroll
            for (int t = 0; t < 2; ++t) gll16(srcB[t] + k1, Bs[nb] + doffB[t]);
        }
        const short* as = As[kt & 1];
        const short* bs = Bs[kt & 1];
        short8 af[8], bfr[4];
        #pragma unroll
        for (int i = 0; i < 8; ++i) af[i] = *(const short8*)(as + offA[i]);
        #pragma unroll
        for (int j = 0; j < 4; ++j) bfr[j] = *(const short8*)(bs + offB[j]);
        #pragma unroll
        for (int i = 0; i < 8; ++i)
            #pragma unroll
            for (int j = 0; j < 4; ++j)
                acc[i][j] = __builtin_amdgcn_mfma_f32_16x16x32_bf16(af[i], bfr[j], acc[i][j], 0, 0, 0);
        __syncthreads();
    }

    #pragma unroll
    for (int j = 0; j < 4; ++j) {
        int ng = n0 + wn + j * 16 + l15;
        int mat = ng >> 10;
        int nl = ng & 1023;
        float bv = (mat == 0) ? b0[nl] : (mat == 1) ? b1[nl] : b2[nl];
        int hh = nl >> 6, dd = nl & 63;
        if (mat == 2) {
            // V -> Vt [BH][64][2048]: 4 consecutive rows r = 4 consecutive s.
            #pragma unroll
            for (int i = 0; i < 8; ++i) {
                int mg0 = m0 + wm + i * 16 + quad * 4;
                int bb = mg0 >> 11, ss0 = mg0 & 2047;
                short4 vv;
                vv.x = f2b(acc[i][j][0] + bv);
                vv.y = f2b(acc[i][j][1] + bv);
                vv.z = f2b(acc[i][j][2] + bv);
                vv.w = f2b(acc[i][j][3] + bv);
                *(short4*)&Vo[((size_t)(bb * 16 + hh) * 64 + dd) * 2048 + ss0] = vv;
            }
        } else {
            short* dst = (mat == 0) ? Qo : Ko;
            float scl = (mat == 0) ? 0.18033688011112042f : 1.0f;  // log2(e)/8 folded into Q
            #pragma unroll
            for (int i = 0; i < 8; ++i)
                #pragma unroll
                for (int r = 0; r < 4; ++r) {
                    int mg = m0 + wm + i * 16 + quad * 4 + r;
                    int bb = mg >> 11, ss = mg & 2047;
                    dst[(((size_t)(bb * 16 + hh)) * 2048 + ss) * 64 + dd] = f2b((acc[i][j][r] + bv) * scl);
                }
        }
    }
}

// ---- proven 128x128 MFMA GEMM (kept for the output projection, mode 1) ------
__global__ __launch_bounds__(256) void mfma_gemm_kernel(
    const short* __restrict__ A, const short* __restrict__ Bt,
    const float* __restrict__ b0,
    float* __restrict__ Co, int K)
{
    __shared__ __align__(16) short As[2][128 * 32];
    __shared__ __align__(16) short Bs[2][128 * 32];

    const int tid = threadIdx.x;
    const int lane = tid & 63;
    const int w = tid >> 6;
    const int quad = lane >> 4;
    const int l15 = lane & 15;
    const int wm = (w & 1) * 64;
    const int wn = (w >> 1) * 64;
    const int m0 = blockIdx.y * 128;
    const int n0 = blockIdx.x * 128;

    const int rl = lane >> 2;
    const int cl = lane & 3;
    const short* srcA[2]; const short* srcB[2];
    int doff[2];
    #pragma unroll
    for (int t = 0; t < 2; ++t) {
        int row = w * 32 + t * 16 + rl;
        int sc = cl ^ (row & 3);
        srcA[t] = A  + (size_t)(m0 + row) * K + sc * 8;
        srcB[t] = Bt + (size_t)(n0 + row) * K + sc * 8;
        doff[t] = (w * 32 + t * 16) * 32;
    }

    int offA[4], offB[4];
    #pragma unroll
    for (int i = 0; i < 4; ++i) {
        int m = wm + i * 16 + l15;
        offA[i] = m * 32 + ((quad ^ (m & 3)) * 8);
        int n = wn + i * 16 + l15;
        offB[i] = n * 32 + ((quad ^ (n & 3)) * 8);
    }

    f32x4 acc[4][4];
    #pragma unroll
    for (int i = 0; i < 4; ++i)
        #pragma unroll
        for (int j = 0; j < 4; ++j)
            acc[i][j] = (f32x4){0.f, 0.f, 0.f, 0.f};

    #pragma unroll
    for (int t = 0; t < 2; ++t) {
        gll16(srcA[t], As[0] + doff[t]);
        gll16(srcB[t], Bs[0] + doff[t]);
    }
    __syncthreads();

    const int KT = K >> 5;
    for (int kt = 0; kt < KT; ++kt) {
        if (kt + 1 < KT) {
            int k1 = (kt + 1) << 5;
            int nb = (kt + 1) & 1;
            #pragma unroll
            for (int t = 0; t < 2; ++t) {
                gll16(srcA[t] + k1, As[nb] + doff[t]);
                gll16(srcB[t] + k1, Bs[nb] + doff[t]);
            }
        }
        const short* as = As[kt & 1];
        const short* bs = Bs[kt & 1];
        short8 af[4], bfr[4];
        #pragma unroll
        for (int i = 0; i < 4; ++i) af[i] = *(const short8*)(as + offA[i]);
        #pragma unroll
        for (int j = 0; j < 4; ++j) bfr[j] = *(const short8*)(bs + offB[j]);
        #pragma unroll
        for (int i = 0; i < 4; ++i)
            #pragma unroll
            for (int j = 0; j < 4; ++j)
                acc[i][j] = __builtin_amdgcn_mfma_f32_16x16x32_bf16(af[i], bfr[j], acc[i][j], 0, 0, 0);
        __syncthreads();
    }

    #pragma unroll
    for (int j = 0; j < 4; ++j) {
        int ng = n0 + wn + j * 16 + l15;
        float bv = b0[ng];
        #pragma unroll
        for (int i = 0; i < 4; ++i)
            #pragma unroll
            for (int r = 0; r < 4; ++r) {
                int mg = m0 + wm + i * 16 + quad * 4 + r;
                Co[(size_t)mg * 1024 + ng] = acc[i][j][r] + bv;
            }
    }
}

// ---- MFMA flash attention (S^T formulation, Q in registers, no Q/P LDS) -----
// Q,K: [BH][2048][64] bf16 (Q pre-scaled by log2e/8); Vt: [BH][64][2048] bf16
// ctx out: [B][2048][1024] bf16
// Each wave handles TWO q-subtiles (q and q+128): K/V LDS fragments are loaded
// once and feed both, halving LDS-read cycles per unit work and doubling the
// independent dependency chains (latency hiding).
__global__ __launch_bounds__(256) void attn_mfma_kernel(
    const short* __restrict__ Q, const short* __restrict__ Kg,
    const short* __restrict__ Vt, const int* __restrict__ mask,
    short* __restrict__ ctx)
{
    __shared__ __align__(16) short Ks[2][64 * 64];
    __shared__ __align__(16) short Vs[2][64 * 64];   // V^T tile: [d][key]
    __shared__ int msks[2][64];
    __shared__ float LinvA[4][32];
    __shared__ float LinvB[4][32];

    const int tid = threadIdx.x;
    const int lane = tid & 63;
    const int w = tid >> 6;
    const int l31 = lane & 31;
    const int hi = lane >> 5;
    const int bh = blockIdx.x;
    const int q0 = blockIdx.y * 256;
    const int h = bh & 15;
    const int b = bh >> 4;
    const size_t qkbase = (size_t)bh * 2048 * 64;
    const size_t vtbase = (size_t)bh * 64 * 2048;

    const int rl8 = lane >> 3;
    const int cl8 = lane & 7;

    const short* srcK[2]; const short* srcV[2];
    int dstoff[2];
    #pragma unroll
    for (int t = 0; t < 2; ++t) {
        int row = w * 16 + t * 8 + rl8;
        int sc = cl8 ^ (row & 7);
        srcK[t] = Kg + qkbase + (size_t)row * 64 + sc * 8;    // + kt*64 per tile
        srcV[t] = Vt + vtbase + (size_t)row * 2048 + sc * 8;  // + kt   per tile
        dstoff[t] = (w * 16 + t * 8) * 64;
    }

    // stage tile 0
    #pragma unroll
    for (int t = 0; t < 2; ++t) {
        gll16(srcK[t], Ks[0] + dstoff[t]);
        gll16(srcV[t], Vs[0] + dstoff[t]);
    }
    if (tid < 64) msks[0][tid] = mask[b * 2048 + tid];

    // Q B-frags for both q-subtiles: lane n = q, k = d = s*16 + hi*8 + j
    short8 qfa[4], qfb[4];
    {
        const short* qptrA = Q + qkbase + (size_t)(q0 + w * 32 + l31) * 64;
        const short* qptrB = qptrA + 128 * 64;
        #pragma unroll
        for (int s = 0; s < 4; ++s) {
            qfa[s] = *(const short8*)(qptrA + (((s << 1) | hi)) * 8);
            qfb[s] = *(const short8*)(qptrB + (((s << 1) | hi)) * 8);
        }
    }

    // persistent zero C-operand for GEMM1
    f32x16 zz;
    #pragma unroll
    for (int r = 0; r < 16; ++r) zz[r] = 0.f;

    f32x16 oa[2], ob[2];
    #pragma unroll
    for (int ch = 0; ch < 2; ++ch)
        #pragma unroll
        for (int r = 0; r < 16; ++r) { oa[ch][r] = 0.f; ob[ch][r] = 0.f; }
    float lqa[4], lqb[4];
    #pragma unroll
    for (int c = 0; c < 4; ++c) { lqa[c] = 0.f; lqb[c] = 0.f; }

    __syncthreads();

    for (int t = 0; t < 32; ++t) {
        const int bidx = t & 1;
        if (t + 1 < 32) {
            const int nb = (t + 1) & 1;
            const int kt1 = (t + 1) * 64;
            #pragma unroll
            for (int s = 0; s < 2; ++s) {
                gll16(srcK[s] + (size_t)kt1 * 64, Ks[nb] + dstoff[s]);
                gll16(srcV[s] + kt1, Vs[nb] + dstoff[s]);
            }
            if (tid < 64) msks[nb][tid] = mask[b * 2048 + kt1 + tid];
        }

        const short* ks = Ks[bidx];
        const short* vs = Vs[bidx];
        unsigned long long bz = __ballot(msks[bidx][lane] == 0);

        #pragma unroll
        for (int km = 0; km < 2; ++km) {
            // GEMM1: S^T (32 keys x 32 q) = K_tile . Q^T, reduce over d = 64
            // K-frags loaded once, feed BOTH q-subtile chains.
            const int kr = km * 32 + l31;
            short8 ka0 = *(const short8*)(ks + kr * 64 + ((hi ^ (l31 & 7))) * 8);
            short8 ka1 = *(const short8*)(ks + kr * 64 + (((2 | hi)) ^ (l31 & 7)) * 8);
            short8 ka2 = *(const short8*)(ks + kr * 64 + (((4 | hi)) ^ (l31 & 7)) * 8);
            short8 ka3 = *(const short8*)(ks + kr * 64 + (((6 | hi)) ^ (l31 & 7)) * 8);
            f32x16 saA = __builtin_amdgcn_mfma_f32_32x32x16_bf16(ka0, qfa[0], zz, 0, 0, 0);
            f32x16 saB = __builtin_amdgcn_mfma_f32_32x32x16_bf16(ka0, qfb[0], zz, 0, 0, 0);
            saA = __builtin_amdgcn_mfma_f32_32x32x16_bf16(ka1, qfa[1], saA, 0, 0, 0);
            saB = __builtin_amdgcn_mfma_f32_32x32x16_bf16(ka1, qfb[1], saB, 0, 0, 0);
            saA = __builtin_amdgcn_mfma_f32_32x32x16_bf16(ka2, qfa[2], saA, 0, 0, 0);
            saB = __builtin_amdgcn_mfma_f32_32x32x16_bf16(ka2, qfb[2], saB, 0, 0, 0);
            saA = __builtin_amdgcn_mfma_f32_32x32x16_bf16(ka3, qfa[3], saA, 0, 0, 0);
            saB = __builtin_amdgcn_mfma_f32_32x32x16_bf16(ka3, qfb[3], saB, 0, 0, 0);

            // p = exp2(s)  (Q carried log2e/8; no max-subtraction)
            float psA[16], psB[16];
            #pragma unroll
            for (int r = 0; r < 16; ++r) { psA[r] = fexp2(saA[r]); psB[r] = fexp2(saB[r]); }
            if (bz) {
                #pragma unroll
                for (int r = 0; r < 16; ++r) {
                    int key = km * 32 + (r & 3) + 8 * (r >> 2) + 4 * hi;
                    if (msks[bidx][key] == 0) { psA[r] = 0.f; psB[r] = 0.f; }
                }
            }
            #pragma unroll
            for (int c = 0; c < 4; ++c) {
                lqa[c] += ((psA[4 * c] + psA[4 * c + 1]) + (psA[4 * c + 2] + psA[4 * c + 3]));
                lqb[c] += ((psB[4 * c] + psB[4 * c + 1]) + (psB[4 * c + 2] + psB[4 * c + 3]));
            }

            // pack to bf16 pairs (HW RNE), lane^32 exchange via permlane32_swap
            unsigned a0 = cvtpk(psA[0],  psA[1]);
            unsigned a1 = cvtpk(psA[2],  psA[3]);
            unsigned a2 = cvtpk(psA[4],  psA[5]);
            unsigned a3 = cvtpk(psA[6],  psA[7]);
            unsigned a4 = cvtpk(psA[8],  psA[9]);
            unsigned a5 = cvtpk(psA[10], psA[11]);
            unsigned a6 = cvtpk(psA[12], psA[13]);
            unsigned a7 = cvtpk(psA[14], psA[15]);
            plswap(a0, a2); plswap(a1, a3); plswap(a4, a6); plswap(a5, a7);
            uint4 A1au, A2au;
            A1au.x = a0; A1au.y = a1; A1au.z = a2; A1au.w = a3;
            A2au.x = a4; A2au.y = a5; A2au.z = a6; A2au.w = a7;
            short8 A1a = __builtin_bit_cast(short8, A1au);
            short8 A2a = __builtin_bit_cast(short8, A2au);

            unsigned g0 = cvtpk(psB[0],  psB[1]);
            unsigned g1 = cvtpk(psB[2],  psB[3]);
            unsigned g2 = cvtpk(psB[4],  psB[5]);
            unsigned g3 = cvtpk(psB[6],  psB[7]);
            unsigned g4 = cvtpk(psB[8],  psB[9]);
            unsigned g5 = cvtpk(psB[10], psB[11]);
            unsigned g6 = cvtpk(psB[12], psB[13]);
            unsigned g7 = cvtpk(psB[14], psB[15]);
            plswap(g0, g2); plswap(g1, g3); plswap(g4, g6); plswap(g5, g7);
            uint4 B1u, B2u;
            B1u.x = g0; B1u.y = g1; B1u.z = g2; B1u.w = g3;
            B2u.x = g4; B2u.y = g5; B2u.z = g6; B2u.w = g7;
            short8 A1b = __builtin_bit_cast(short8, B1u);
            short8 A2b = __builtin_bit_cast(short8, B2u);

            // GEMM2: V-frags loaded once, feed BOTH q-subtile accumulators.
            #pragma unroll
            for (int ch = 0; ch < 2; ++ch) {
                const int d = ch * 32 + l31;
                short8 vb0 = *(const short8*)(vs + d * 64 + (((km * 4) | hi) ^ (d & 7)) * 8);
                short8 vb1 = *(const short8*)(vs + d * 64 + (((km * 4 + 2) | hi) ^ (d & 7)) * 8);
                oa[ch] = __builtin_amdgcn_mfma_f32_32x32x16_bf16(A1a, vb0, oa[ch], 0, 0, 0);
                ob[ch] = __builtin_amdgcn_mfma_f32_32x32x16_bf16(A1b, vb0, ob[ch], 0, 0, 0);
                oa[ch] = __builtin_amdgcn_mfma_f32_32x32x16_bf16(A2a, vb1, oa[ch], 0, 0, 0);
                ob[ch] = __builtin_amdgcn_mfma_f32_32x32x16_bf16(A2b, vb1, ob[ch], 0, 0, 0);
            }
        }
        __syncthreads();
    }

    // epilogue: combine half-key sums (lane^32), normalize, store (both sets)
    float lsumA = (lqa[0] + lqa[1]) + (lqa[2] + lqa[3]);
    float ltotA = lsumA + __shfl_xor(lsumA, 32);
    float lsumB = (lqb[0] + lqb[1]) + (lqb[2] + lqb[3]);
    float ltotB = lsumB + __shfl_xor(lsumB, 32);
    if (hi == 0) {
        LinvA[w][l31] = 1.0f / ltotA;
        LinvB[w][l31] = 1.0f / ltotB;
    }
    asm volatile("s_waitcnt lgkmcnt(0)" ::: "memory");
    float invrA[16], invrB[16];
    #pragma unroll
    for (int r = 0; r < 16; ++r) {
        int rowq = (r & 3) + 8 * (r >> 2) + 4 * hi;
        invrA[r] = LinvA[w][rowq];
        invrB[r] = LinvB[w][rowq];
    }
    #pragma unroll
    for (int ch = 0; ch < 2; ++ch)
        #pragma unroll
        for (int r = 0; r < 16; ++r) {
            int rowq = (r & 3) + 8 * (r >> 2) + 4 * hi;
            int qg = q0 + w * 32 + rowq;
            size_t base = ((size_t)b * 2048 + qg) * 1024 + h * 64 + ch * 32 + l31;
            ctx[base] = f2b(oa[ch][r] * invrA[r]);
            ctx[base + (size_t)128 * 1024] = f2b(ob[ch][r] * invrB[r]);
        }
}

// ---- launch -----------------------------------------------------------------

extern "C" void kernel_launch(void* const* d_in, const int* in_sizes, int n_in,
                              void* d_out, int out_size, void* d_ws, size_t ws_size,
                              hipStream_t stream) {
    const size_t ME = (size_t)8192 * 1024;   // 8,388,608 elements

    char* ws = (char*)d_ws;
    short* xb    = (short*)ws; ws += ME * 2;                 // x bf16; reused as ctx
    short* wqkvt = (short*)ws; ws += (size_t)3072 * 1024 * 2;
    short* wot   = (short*)ws; ws += (size_t)1024 * 1024 * 2;
    short* Qb    = (short*)ws; ws += ME * 2;
    short* Kb    = (short*)ws; ws += ME * 2;
    short* Vt    = (short*)ws; ws += ME * 2;   // V^T written directly by the QKV GEMM

    xconv_kernel<<<8192, 256, 0, stream>>>((const float4*)d_in[0], xb);
    wconv4_kernel<<<dim3(32, 32, 4), 256, 0, stream>>>(
        (const float*)d_in[2], (const float*)d_in[4],
        (const float*)d_in[6], (const float*)d_in[8], wqkvt, wot);

    mfma_gemm_qkv_kernel<<<dim3(24, 32), 256, 0, stream>>>(
        xb, wqkvt, (const float*)d_in[3], (const float*)d_in[5], (const float*)d_in[7],
        Qb, Kb, Vt, 1024);

    attn_mfma_kernel<<<dim3(64, 8), 256, 0, stream>>>(
        Qb, Kb, Vt, (const int*)d_in[1], xb /* ctx */);

    mfma_gemm_kernel<<<dim3(8, 64), 256, 0, stream>>>(
        xb, wot, (const float*)d_in[9], (float*)d_out, 1024);
}

// Round 11
// 294.221 us; speedup vs baseline: 1.0879x; 1.0046x over previous
//
#include <hip/hip_runtime.h>

typedef __attribute__((ext_vector_type(8)))  short short8;
typedef __attribute__((ext_vector_type(4)))  float f32x4;
typedef __attribute__((ext_vector_type(16))) float f32x16;

__device__ __forceinline__ short f2b(float f) {
    union { float f; unsigned u; } v; v.f = f;
    unsigned r = v.u + 0x7FFF + ((v.u >> 16) & 1);   // RNE
    return (short)(r >> 16);
}

__device__ __forceinline__ float fexp2(float x) {
    float r;
    asm("v_exp_f32 %0, %1" : "=v"(r) : "v"(x));
    return r;
}

// pack two f32 -> one u32 of 2x bf16 (RNE), lo = a, hi = b
__device__ __forceinline__ unsigned cvtpk(float a, float b) {
    unsigned r;
    asm("v_cvt_pk_bf16_f32 %0, %1, %2" : "=v"(r) : "v"(a), "v"(b));
    return r;
}

// v_permlane32_swap_b32: a' = {a.lanes[0:31], b.lanes[0:31]},
//                        b' = {a.lanes[32:63], b.lanes[32:63]}
__device__ __forceinline__ void plswap(unsigned &a, unsigned &b) {
    asm("v_permlane32_swap_b32 %0, %1" : "+v"(a), "+v"(b));
}

__device__ __forceinline__ void gll16(const void* g, void* l) {
    __builtin_amdgcn_global_load_lds(
        (const __attribute__((address_space(1))) void*)g,
        (__attribute__((address_space(3))) void*)l, 16, 0, 0);
}

// ---- fused prep kernel ------------------------------------------------------
// blocks [0, 4096): weight transpose+convert (z = blk>>10, by = (blk>>5)&31,
//                   bx = blk&31) — body identical to the proven wconv4.
// blocks [4096, 12288): x fp32 -> bf16 (i = (blk-4096)*256 + tid) — body
//                   identical to the proven xconv.
__global__ __launch_bounds__(256) void prep_kernel(
    const float4* __restrict__ X, short* __restrict__ xb,
    const float* __restrict__ w0, const float* __restrict__ w1,
    const float* __restrict__ w2, const float* __restrict__ w3,
    short* __restrict__ wqkvt, short* __restrict__ wot) {
    __shared__ float t[32][33];
    int blk = blockIdx.x;
    if (blk < 4096) {
        int z = blk >> 10;
        int by = (blk >> 5) & 31;
        int bx = blk & 31;
        const float* W = (z == 0) ? w0 : (z == 1) ? w1 : (z == 2) ? w2 : w3;
        short* WT = (z < 3) ? wqkvt : wot;
        int row_off = (z < 3) ? z * 1024 : 0;
        int c = threadIdx.x & 31, r0 = threadIdx.x >> 5;
        #pragma unroll
        for (int p = 0; p < 4; ++p) {
            int r = r0 + p * 8;
            t[r][c] = W[(size_t)(by * 32 + r) * 1024 + bx * 32 + c];
        }
        __syncthreads();
        #pragma unroll
        for (int p = 0; p < 4; ++p) {
            int r = r0 + p * 8;
            WT[(size_t)(row_off + bx * 32 + r) * 1024 + by * 32 + c] = f2b(t[c][r]);
        }
    } else {
        int i = (blk - 4096) * 256 + threadIdx.x;
        float4 v = X[i];
        short4 o;
        o.x = f2b(v.x); o.y = f2b(v.y); o.z = f2b(v.z); o.w = f2b(v.w);
        ((short4*)xb)[i] = o;
    }
}

// ---- QKV MFMA GEMM: BM=256 x BN=128, per-wave 128x64 output -----------------
// A-fragment reuse: 12 ds_read_b128 feed 32 MFMA per K-step (vs 8:16) ->
// MFMA-bound instead of LDS-read-bound. Same proven staging idiom / 1 barrier
// per K-step / 4 waves. Scatter epilogue identical to the proven mode-0 path
// (V written directly transposed), only the i-loop extends to 8.
__global__ __launch_bounds__(256, 2) void mfma_gemm_qkv_kernel(
    const short* __restrict__ A, const short* __restrict__ Bt,
    const float* __restrict__ b0, const float* __restrict__ b1,
    const float* __restrict__ b2,
    short* __restrict__ Qo, short* __restrict__ Ko, short* __restrict__ Vo,
    int K)
{
    __shared__ __align__(16) short As[2][256 * 32];   // 32 KB
    __shared__ __align__(16) short Bs[2][128 * 32];   // 16 KB

    const int tid = threadIdx.x;
    const int lane = tid & 63;
    const int w = tid >> 6;
    const int quad = lane >> 4;
    const int l15 = lane & 15;
    const int wm = (w & 1) * 128;
    const int wn = (w >> 1) * 64;
    const int m0 = blockIdx.y * 256;
    const int n0 = blockIdx.x * 128;

    const int rl = lane >> 2;
    const int cl = lane & 3;
    const short* srcA[4]; int doffA[4];
    #pragma unroll
    for (int t = 0; t < 4; ++t) {
        int row = w * 64 + t * 16 + rl;
        int sc = cl ^ (row & 3);
        srcA[t] = A + (size_t)(m0 + row) * K + sc * 8;
        doffA[t] = (w * 64 + t * 16) * 32;
    }
    const short* srcB[2]; int doffB[2];
    #pragma unroll
    for (int t = 0; t < 2; ++t) {
        int row = w * 32 + t * 16 + rl;
        int sc = cl ^ (row & 3);
        srcB[t] = Bt + (size_t)(n0 + row) * K + sc * 8;
        doffB[t] = (w * 32 + t * 16) * 32;
    }

    int offA[8], offB[4];
    #pragma unroll
    for (int i = 0; i < 8; ++i) {
        int m = wm + i * 16 + l15;
        offA[i] = m * 32 + ((quad ^ (m & 3)) * 8);
    }
    #pragma unroll
    for (int j = 0; j < 4; ++j) {
        int n = wn + j * 16 + l15;
        offB[j] = n * 32 + ((quad ^ (n & 3)) * 8);
    }

    f32x4 acc[8][4];
    #pragma unroll
    for (int i = 0; i < 8; ++i)
        #pragma unroll
        for (int j = 0; j < 4; ++j)
            acc[i][j] = (f32x4){0.f, 0.f, 0.f, 0.f};

    #pragma unroll
    for (int t = 0; t < 4; ++t) gll16(srcA[t], As[0] + doffA[t]);
    #pragma unroll
    for (int t = 0; t < 2; ++t) gll16(srcB[t], Bs[0] + doffB[t]);
    __syncthreads();

    const int KT = K >> 5;
    for (int kt = 0; kt < KT; ++kt) {
        if (kt + 1 < KT) {
            int k1 = (kt + 1) << 5;
            int nb = (kt + 1) & 1;
            #pragma unroll
            for (int t = 0; t < 4; ++t) gll16(srcA[t] + k1, As[nb] + doffA[t]);
            #pragma unroll
            for (int t = 0; t < 2; ++t) gll16(srcB[t] + k1, Bs[nb] + doffB[t]);
        }
        const short* as = As[kt & 1];
        const short* bs = Bs[kt & 1];
        short8 af[8], bfr[4];
        #pragma unroll
        for (int i = 0; i < 8; ++i) af[i] = *(const short8*)(as + offA[i]);
        #pragma unroll
        for (int j = 0; j < 4; ++j) bfr[j] = *(const short8*)(bs + offB[j]);
        #pragma unroll
        for (int i = 0; i < 8; ++i)
            #pragma unroll
            for (int j = 0; j < 4; ++j)
                acc[i][j] = __builtin_amdgcn_mfma_f32_16x16x32_bf16(af[i], bfr[j], acc[i][j], 0, 0, 0);
        __syncthreads();
    }

    #pragma unroll
    for (int j = 0; j < 4; ++j) {
        int ng = n0 + wn + j * 16 + l15;
        int mat = ng >> 10;
        int nl = ng & 1023;
        float bv = (mat == 0) ? b0[nl] : (mat == 1) ? b1[nl] : b2[nl];
        int hh = nl >> 6, dd = nl & 63;
        if (mat == 2) {
            // V -> Vt [BH][64][2048]: 4 consecutive rows r = 4 consecutive s.
            #pragma unroll
            for (int i = 0; i < 8; ++i) {
                int mg0 = m0 + wm + i * 16 + quad * 4;
                int bb = mg0 >> 11, ss0 = mg0 & 2047;
                short4 vv;
                vv.x = f2b(acc[i][j][0] + bv);
                vv.y = f2b(acc[i][j][1] + bv);
                vv.z = f2b(acc[i][j][2] + bv);
                vv.w = f2b(acc[i][j][3] + bv);
                *(short4*)&Vo[((size_t)(bb * 16 + hh) * 64 + dd) * 2048 + ss0] = vv;
            }
        } else {
            short* dst = (mat == 0) ? Qo : Ko;
            float scl = (mat == 0) ? 0.18033688011112042f : 1.0f;  // log2(e)/8 folded into Q
            #pragma unroll
            for (int i = 0; i < 8; ++i)
                #pragma unroll
                for (int r = 0; r < 4; ++r) {
                    int mg = m0 + wm + i * 16 + quad * 4 + r;
                    int bb = mg >> 11, ss = mg & 2047;
                    dst[(((size_t)(bb * 16 + hh)) * 2048 + ss) * 64 + dd] = f2b((acc[i][j][r] + bv) * scl);
                }
        }
    }
}

// ---- proven 128x128 MFMA GEMM (output projection) ---------------------------
__global__ __launch_bounds__(256) void mfma_gemm_kernel(
    const short* __restrict__ A, const short* __restrict__ Bt,
    const float* __restrict__ b0,
    float* __restrict__ Co, int K)
{
    __shared__ __align__(16) short As[2][128 * 32];
    __shared__ __align__(16) short Bs[2][128 * 32];

    const int tid = threadIdx.x;
    const int lane = tid & 63;
    const int w = tid >> 6;
    const int quad = lane >> 4;
    const int l15 = lane & 15;
    const int wm = (w & 1) * 64;
    const int wn = (w >> 1) * 64;
    const int m0 = blockIdx.y * 128;
    const int n0 = blockIdx.x * 128;

    const int rl = lane >> 2;
    const int cl = lane & 3;
    const short* srcA[2]; const short* srcB[2];
    int doff[2];
    #pragma unroll
    for (int t = 0; t < 2; ++t) {
        int row = w * 32 + t * 16 + rl;
        int sc = cl ^ (row & 3);
        srcA[t] = A  + (size_t)(m0 + row) * K + sc * 8;
        srcB[t] = Bt + (size_t)(n0 + row) * K + sc * 8;
        doff[t] = (w * 32 + t * 16) * 32;
    }

    int offA[4], offB[4];
    #pragma unroll
    for (int i = 0; i < 4; ++i) {
        int m = wm + i * 16 + l15;
        offA[i] = m * 32 + ((quad ^ (m & 3)) * 8);
        int n = wn + i * 16 + l15;
        offB[i] = n * 32 + ((quad ^ (n & 3)) * 8);
    }

    f32x4 acc[4][4];
    #pragma unroll
    for (int i = 0; i < 4; ++i)
        #pragma unroll
        for (int j = 0; j < 4; ++j)
            acc[i][j] = (f32x4){0.f, 0.f, 0.f, 0.f};

    #pragma unroll
    for (int t = 0; t < 2; ++t) {
        gll16(srcA[t], As[0] + doff[t]);
        gll16(srcB[t], Bs[0] + doff[t]);
    }
    __syncthreads();

    const int KT = K >> 5;
    for (int kt = 0; kt < KT; ++kt) {
        if (kt + 1 < KT) {
            int k1 = (kt + 1) << 5;
            int nb = (kt + 1) & 1;
            #pragma unroll
            for (int t = 0; t < 2; ++t) {
                gll16(srcA[t] + k1, As[nb] + doff[t]);
                gll16(srcB[t] + k1, Bs[nb] + doff[t]);
            }
        }
        const short* as = As[kt & 1];
        const short* bs = Bs[kt & 1];
        short8 af[4], bfr[4];
        #pragma unroll
        for (int i = 0; i < 4; ++i) af[i] = *(const short8*)(as + offA[i]);
        #pragma unroll
        for (int j = 0; j < 4; ++j) bfr[j] = *(const short8*)(bs + offB[j]);
        #pragma unroll
        for (int i = 0; i < 4; ++i)
            #pragma unroll
            for (int j = 0; j < 4; ++j)
                acc[i][j] = __builtin_amdgcn_mfma_f32_16x16x32_bf16(af[i], bfr[j], acc[i][j], 0, 0, 0);
        __syncthreads();
    }

    #pragma unroll
    for (int j = 0; j < 4; ++j) {
        int ng = n0 + wn + j * 16 + l15;
        float bv = b0[ng];
        #pragma unroll
        for (int i = 0; i < 4; ++i)
            #pragma unroll
            for (int r = 0; r < 4; ++r) {
                int mg = m0 + wm + i * 16 + quad * 4 + r;
                Co[(size_t)mg * 1024 + ng] = acc[i][j][r] + bv;
            }
    }
}

// ---- MFMA flash attention (S^T formulation, Q in registers, no Q/P LDS) -----
// Q,K: [BH][2048][64] bf16 (Q pre-scaled by log2e/8); Vt: [BH][64][2048] bf16
// ctx out: [B][2048][1024] bf16
// Each wave handles TWO q-subtiles (q and q+128): K/V LDS fragments are loaded
// once and feed both, halving LDS-read cycles per unit work and doubling the
// independent dependency chains (latency hiding).
__global__ __launch_bounds__(256) void attn_mfma_kernel(
    const short* __restrict__ Q, const short* __restrict__ Kg,
    const short* __restrict__ Vt, const int* __restrict__ mask,
    short* __restrict__ ctx)
{
    __shared__ __align__(16) short Ks[2][64 * 64];
    __shared__ __align__(16) short Vs[2][64 * 64];   // V^T tile: [d][key]
    __shared__ int msks[2][64];
    __shared__ float LinvA[4][32];
    __shared__ float LinvB[4][32];

    const int tid = threadIdx.x;
    const int lane = tid & 63;
    const int w = tid >> 6;
    const int l31 = lane & 31;
    const int hi = lane >> 5;
    const int bh = blockIdx.x;
    const int q0 = blockIdx.y * 256;
    const int h = bh & 15;
    const int b = bh >> 4;
    const size_t qkbase = (size_t)bh * 2048 * 64;
    const size_t vtbase = (size_t)bh * 64 * 2048;

    const int rl8 = lane >> 3;
    const int cl8 = lane & 7;

    const short* srcK[2]; const short* srcV[2];
    int dstoff[2];
    #pragma unroll
    for (int t = 0; t < 2; ++t) {
        int row = w * 16 + t * 8 + rl8;
        int sc = cl8 ^ (row & 7);
        srcK[t] = Kg + qkbase + (size_t)row * 64 + sc * 8;    // + kt*64 per tile
        srcV[t] = Vt + vtbase + (size_t)row * 2048 + sc * 8;  // + kt   per tile
        dstoff[t] = (w * 16 + t * 8) * 64;
    }

    // stage tile 0
    #pragma unroll
    for (int t = 0; t < 2; ++t) {
        gll16(srcK[t], Ks[0] + dstoff[t]);
        gll16(srcV[t], Vs[0] + dstoff[t]);
    }
    if (tid < 64) msks[0][tid] = mask[b * 2048 + tid];

    // Q B-frags for both q-subtiles: lane n = q, k = d = s*16 + hi*8 + j
    short8 qfa[4], qfb[4];
    {
        const short* qptrA = Q + qkbase + (size_t)(q0 + w * 32 + l31) * 64;
        const short* qptrB = qptrA + 128 * 64;
        #pragma unroll
        for (int s = 0; s < 4; ++s) {
            qfa[s] = *(const short8*)(qptrA + (((s << 1) | hi)) * 8);
            qfb[s] = *(const short8*)(qptrB + (((s << 1) | hi)) * 8);
        }
    }

    // persistent zero C-operand for GEMM1
    f32x16 zz;
    #pragma unroll
    for (int r = 0; r < 16; ++r) zz[r] = 0.f;

    f32x16 oa[2], ob[2];
    #pragma unroll
    for (int ch = 0; ch < 2; ++ch)
        #pragma unroll
        for (int r = 0; r < 16; ++r) { oa[ch][r] = 0.f; ob[ch][r] = 0.f; }
    float lqa[4], lqb[4];
    #pragma unroll
    for (int c = 0; c < 4; ++c) { lqa[c] = 0.f; lqb[c] = 0.f; }

    __syncthreads();

    for (int t = 0; t < 32; ++t) {
        const int bidx = t & 1;
        if (t + 1 < 32) {
            const int nb = (t + 1) & 1;
            const int kt1 = (t + 1) * 64;
            #pragma unroll
            for (int s = 0; s < 2; ++s) {
                gll16(srcK[s] + (size_t)kt1 * 64, Ks[nb] + dstoff[s]);
                gll16(srcV[s] + kt1, Vs[nb] + dstoff[s]);
            }
            if (tid < 64) msks[nb][tid] = mask[b * 2048 + kt1 + tid];
        }

        const short* ks = Ks[bidx];
        const short* vs = Vs[bidx];
        unsigned long long bz = __ballot(msks[bidx][lane] == 0);

        #pragma unroll
        for (int km = 0; km < 2; ++km) {
            // GEMM1: S^T (32 keys x 32 q) = K_tile . Q^T, reduce over d = 64
            // K-frags loaded once, feed BOTH q-subtile chains.
            const int kr = km * 32 + l31;
            short8 ka0 = *(const short8*)(ks + kr * 64 + ((hi ^ (l31 & 7))) * 8);
            short8 ka1 = *(const short8*)(ks + kr * 64 + (((2 | hi)) ^ (l31 & 7)) * 8);
            short8 ka2 = *(const short8*)(ks + kr * 64 + (((4 | hi)) ^ (l31 & 7)) * 8);
            short8 ka3 = *(const short8*)(ks + kr * 64 + (((6 | hi)) ^ (l31 & 7)) * 8);
            f32x16 saA = __builtin_amdgcn_mfma_f32_32x32x16_bf16(ka0, qfa[0], zz, 0, 0, 0);
            f32x16 saB = __builtin_amdgcn_mfma_f32_32x32x16_bf16(ka0, qfb[0], zz, 0, 0, 0);
            saA = __builtin_amdgcn_mfma_f32_32x32x16_bf16(ka1, qfa[1], saA, 0, 0, 0);
            saB = __builtin_amdgcn_mfma_f32_32x32x16_bf16(ka1, qfb[1], saB, 0, 0, 0);
            saA = __builtin_amdgcn_mfma_f32_32x32x16_bf16(ka2, qfa[2], saA, 0, 0, 0);
            saB = __builtin_amdgcn_mfma_f32_32x32x16_bf16(ka2, qfb[2], saB, 0, 0, 0);
            saA = __builtin_amdgcn_mfma_f32_32x32x16_bf16(ka3, qfa[3], saA, 0, 0, 0);
            saB = __builtin_amdgcn_mfma_f32_32x32x16_bf16(ka3, qfb[3], saB, 0, 0, 0);

            // p = exp2(s)  (Q carried log2e/8; no max-subtraction)
            float psA[16], psB[16];
            #pragma unroll
            for (int r = 0; r < 16; ++r) { psA[r] = fexp2(saA[r]); psB[r] = fexp2(saB[r]); }
            if (bz) {
                #pragma unroll
                for (int r = 0; r < 16; ++r) {
                    int key = km * 32 + (r & 3) + 8 * (r >> 2) + 4 * hi;
                    if (msks[bidx][key] == 0) { psA[r] = 0.f; psB[r] = 0.f; }
                }
            }
            #pragma unroll
            for (int c = 0; c < 4; ++c) {
                lqa[c] += ((psA[4 * c] + psA[4 * c + 1]) + (psA[4 * c + 2] + psA[4 * c + 3]));
                lqb[c] += ((psB[4 * c] + psB[4 * c + 1]) + (psB[4 * c + 2] + psB[4 * c + 3]));
            }

            // pack to bf16 pairs (HW RNE), lane^32 exchange via permlane32_swap
            unsigned a0 = cvtpk(psA[0],  psA[1]);
            unsigned a1 = cvtpk(psA[2],  psA[3]);
            unsigned a2 = cvtpk(psA[4],  psA[5]);
            unsigned a3 = cvtpk(psA[6],  psA[7]);
            unsigned a4 = cvtpk(psA[8],  psA[9]);
            unsigned a5 = cvtpk(psA[10], psA[11]);
            unsigned a6 = cvtpk(psA[12], psA[13]);
            unsigned a7 = cvtpk(psA[14], psA[15]);
            plswap(a0, a2); plswap(a1, a3); plswap(a4, a6); plswap(a5, a7);
            uint4 A1au, A2au;
            A1au.x = a0; A1au.y = a1; A1au.z = a2; A1au.w = a3;
            A2au.x = a4; A2au.y = a5; A2au.z = a6; A2au.w = a7;
            short8 A1a = __builtin_bit_cast(short8, A1au);
            short8 A2a = __builtin_bit_cast(short8, A2au);

            unsigned g0 = cvtpk(psB[0],  psB[1]);
            unsigned g1 = cvtpk(psB[2],  psB[3]);
            unsigned g2 = cvtpk(psB[4],  psB[5]);
            unsigned g3 = cvtpk(psB[6],  psB[7]);
            unsigned g4 = cvtpk(psB[8],  psB[9]);
            unsigned g5 = cvtpk(psB[10], psB[11]);
            unsigned g6 = cvtpk(psB[12], psB[13]);
            unsigned g7 = cvtpk(psB[14], psB[15]);
            plswap(g0, g2); plswap(g1, g3); plswap(g4, g6); plswap(g5, g7);
            uint4 B1u, B2u;
            B1u.x = g0; B1u.y = g1; B1u.z = g2; B1u.w = g3;
            B2u.x = g4; B2u.y = g5; B2u.z = g6; B2u.w = g7;
            short8 A1b = __builtin_bit_cast(short8, B1u);
            short8 A2b = __builtin_bit_cast(short8, B2u);

            // GEMM2: V-frags loaded once, feed BOTH q-subtile accumulators.
            #pragma unroll
            for (int ch = 0; ch < 2; ++ch) {
                const int d = ch * 32 + l31;
                short8 vb0 = *(const short8*)(vs + d * 64 + (((km * 4) | hi) ^ (d & 7)) * 8);
                short8 vb1 = *(const short8*)(vs + d * 64 + (((km * 4 + 2) | hi) ^ (d & 7)) * 8);
                oa[ch] = __builtin_amdgcn_mfma_f32_32x32x16_bf16(A1a, vb0, oa[ch], 0, 0, 0);
                ob[ch] = __builtin_amdgcn_mfma_f32_32x32x16_bf16(A1b, vb0, ob[ch], 0, 0, 0);
                oa[ch] = __builtin_amdgcn_mfma_f32_32x32x16_bf16(A2a, vb1, oa[ch], 0, 0, 0);
                ob[ch] = __builtin_amdgcn_mfma_f32_32x32x16_bf16(A2b, vb1, ob[ch], 0, 0, 0);
            }
        }
        __syncthreads();
    }

    // epilogue: combine half-key sums (lane^32), normalize, store (both sets)
    float lsumA = (lqa[0] + lqa[1]) + (lqa[2] + lqa[3]);
    float ltotA = lsumA + __shfl_xor(lsumA, 32);
    float lsumB = (lqb[0] + lqb[1]) + (lqb[2] + lqb[3]);
    float ltotB = lsumB + __shfl_xor(lsumB, 32);
    if (hi == 0) {
        LinvA[w][l31] = 1.0f / ltotA;
        LinvB[w][l31] = 1.0f / ltotB;
    }
    asm volatile("s_waitcnt lgkmcnt(0)" ::: "memory");
    float invrA[16], invrB[16];
    #pragma unroll
    for (int r = 0; r < 16; ++r) {
        int rowq = (r & 3) + 8 * (r >> 2) + 4 * hi;
        invrA[r] = LinvA[w][rowq];
        invrB[r] = LinvB[w][rowq];
    }
    #pragma unroll
    for (int ch = 0; ch < 2; ++ch)
        #pragma unroll
        for (int r = 0; r < 16; ++r) {
            int rowq = (r & 3) + 8 * (r >> 2) + 4 * hi;
            int qg = q0 + w * 32 + rowq;
            size_t base = ((size_t)b * 2048 + qg) * 1024 + h * 64 + ch * 32 + l31;
            ctx[base] = f2b(oa[ch][r] * invrA[r]);
            ctx[base + (size_t)128 * 1024] = f2b(ob[ch][r] * invrB[r]);
        }
}

// ---- launch -----------------------------------------------------------------

extern "C" void kernel_launch(void* const* d_in, const int* in_sizes, int n_in,
                              void* d_out, int out_size, void* d_ws, size_t ws_size,
                              hipStream_t stream) {
    const size_t ME = (size_t)8192 * 1024;   // 8,388,608 elements

    char* ws = (char*)d_ws;
    short* xb    = (short*)ws; ws += ME * 2;                 // x bf16; reused as ctx
    short* wqkvt = (short*)ws; ws += (size_t)3072 * 1024 * 2;
    short* wot   = (short*)ws; ws += (size_t)1024 * 1024 * 2;
    short* Qb    = (short*)ws; ws += ME * 2;
    short* Kb    = (short*)ws; ws += ME * 2;
    short* Vt    = (short*)ws; ws += ME * 2;   // V^T written directly by the QKV GEMM

    prep_kernel<<<12288, 256, 0, stream>>>(
        (const float4*)d_in[0], xb,
        (const float*)d_in[2], (const float*)d_in[4],
        (const float*)d_in[6], (const float*)d_in[8], wqkvt, wot);

    mfma_gemm_qkv_kernel<<<dim3(24, 32), 256, 0, stream>>>(
        xb, wqkvt, (const float*)d_in[3], (const float*)d_in[5], (const float*)d_in[7],
        Qb, Kb, Vt, 1024);

    attn_mfma_kernel<<<dim3(64, 8), 256, 0, stream>>>(
        Qb, Kb, Vt, (const int*)d_in[1], xb /* ctx */);

    mfma_gemm_kernel<<<dim3(8, 64), 256, 0, stream>>>(
        xb, wot, (const float*)d_in[9], (float*)d_out, 1024);
}